// Round 1
// 203.716 us; speedup vs baseline: 1.0077x; 1.0077x over previous
//
#include <hip/hip_runtime.h>
#include <hip/hip_bf16.h>

// 0-dim Rips persistence deaths == Euclidean MST edge lengths.
// N=4096, DIM=64, output sorted ascending (4095 values).
//
// R11 (on verified R10): structural trim of the typical path.
//  - Compact threshold raised 256 -> 512. Boruvka halves comps per round,
//    so C <= 512 is GUARANTEED after round 2 => hook2 always compacts and
//    scan3/hook3 (R10's guarded fallback dispatches) are deleted. 12 -> 10
//    dispatches. bor_finish moves to u64 keys (w16<<20|lo<<10|hi), M is
//    512-wide (1 MB).
//  - M init moved out of the single-block hook into prep (1024x256 threads
//    == exactly 512*512 entries, one store each).
//  - prep dtype probe parallelized: 1 element/thread + __syncthreads_and
//    (was a 256-load serial chain on thread 0 of every block).
//  - hook: nroots counting removed (only TRY mode needed it).
//  - rank_sort: 4 pivots per block (1024 blocks instead of 4095), packed
//    u64 reductions; 1/4 the edges[] L2 broadcast traffic.
// Everything else identical to verified R10.
//
// Pipeline:
//   prep(+M init) ; dist_mfma(+scan0) ; hook0 ; scan1 ; hook1 ; scan2 ;
//   hook2(force-compact, C<=512 guaranteed) ; bor_project ; bor_finish ;
//   rank_sort -> d_out
// Fallback: R1 Prim (+VALU dist) if ws too small.
//
// Fixed-floor note (R8-R10 evidence): top-5 dispatches are exclusively the
// harness's 256 MiB ws re-poison fills (47 us each, ~70% HBM peak); our
// dispatches sum to ~70-90 us; total includes a ~130 us floor outside
// kernel control.

#define NPTS 4096
#define SENT 1e30f
#define KINF 0xFFFFFFFFFFFFFFFFull
#define INV32 0xFFFFFFFFu
#define SCAN_ROWS 2
#define SCAN_BLOCKS (NPTS / SCAN_ROWS)
#define CMAX 512          // compact component capacity (C <= 512 after round 2)

// hook modes
#define HOOK_NORMAL 0
#define HOOK_FORCE_COMPACT 1

typedef short short8 __attribute__((ext_vector_type(8)));
typedef float f32x4 __attribute__((ext_vector_type(4)));

__device__ __forceinline__ float bfbits2f(unsigned int u16) {
  union { unsigned int u; float f; } c;
  c.u = u16 << 16;
  return c.f;
}

__device__ bool data_is_bf16(const unsigned short* p) {
  bool bf = true;
  for (int i = 0; i < 256; ++i) {
    float f = bfbits2f((unsigned int)p[i]);
    if (!(f > -1e6f && f < 1e6f)) bf = false;  // catches huge and NaN
  }
  return bf;
}

// ---------------------------------------------------------------------------
// prep (+ fused Boruvka init): one wave per point row. Convert to bf16 P,
// compute sq[]; init comp/comp16/parent/cheapest/edges-tail/cnt/M.
// Dtype probe: thread i checks element i (same 256 elems in every block),
// combined with __syncthreads_and -- no serial chain.
// ---------------------------------------------------------------------------
__global__ __launch_bounds__(256) void prep_kernel(
    const void* pts_raw, unsigned short* Pb, float* sq, int* comp,
    unsigned short* comp16, int* parent, unsigned long long* cheapest,
    float* edges, unsigned* cnt, unsigned* M) {
  float pf = bfbits2f((unsigned int)((const unsigned short*)pts_raw)[threadIdx.x]);
  const bool bfs = (bool)__syncthreads_and((int)(pf > -1e6f && pf < 1e6f));

  const int g = blockIdx.x * 256 + threadIdx.x;
  if (g < NPTS) {
    comp[g] = g;
    comp16[g] = (unsigned short)g;
    parent[g] = g;               // hook 0 runs without a preceding bor_scan
    cheapest[g] = KINF;
  }
  M[g] = INV32;                  // 1024*256 threads == 512*512 entries exactly
  if (g == NPTS - 1) edges[NPTS - 1] = SENT;  // rank_sort tail (0xAA is neg!)
  if (g == 0) {
    cnt[0] = 0u;               // edge counter
    cnt[1] = 0u;               // done flag
    cnt[2] = bfs ? 1u : 0u;    // dtype flag
    cnt[3] = 0u;               // compact component count (0 = not compacted)
  }

  const int row = g >> 6;
  const int lane = threadIdx.x & 63;

  unsigned short ub;
  if (bfs) {
    ub = ((const unsigned short*)pts_raw)[row * 64 + lane];
  } else {
    __hip_bfloat16 h = __float2bfloat16(((const float*)pts_raw)[row * 64 + lane]);
    ub = *(unsigned short*)&h;
  }
  Pb[row * 64 + lane] = ub;

  float v = bfbits2f((unsigned int)ub);
  float s = v * v;
#pragma unroll
  for (int m = 1; m < 64; m <<= 1) s += __shfl_xor(s, m);
  if (lane == 0) sq[row] = s;
}

// ---------------------------------------------------------------------------
// dist via MFMA + fused round-0 scan. Block (bx,by) -> 64x64 tile; after the
// coalesced store, the LDS tile is reduced per-row (excluding the diagonal)
// and atomicMin'd into cheapest[] with the standard u64 edge key.
// ---------------------------------------------------------------------------
__global__ __launch_bounds__(256) void dist_mfma(const unsigned short* Pb,
                                                 const float* sq,
                                                 unsigned short* Dbf,
                                                 unsigned long long* cheapest) {
  __shared__ unsigned short tile[64 * 72];   // padded: stride 72 shorts

  const int t = threadIdx.x;
  const int w = t >> 6, lane = t & 63;
  const int quad = lane >> 4, l16 = lane & 15;
  const int rbase = blockIdx.y * 64 + w * 16;
  const int cbase = blockIdx.x * 64;

  const short8* Pv = (const short8*)Pb;      // row r = Pv[r*8 + k/8]
  short8 a0 = Pv[(rbase + l16) * 8 + quad];        // k = quad*8 .. +8
  short8 a1 = Pv[(rbase + l16) * 8 + quad + 4];    // k = 32+quad*8 .. +8

  f32x4 acc[4];
#pragma unroll
  for (int c = 0; c < 4; ++c) {
    short8 b0 = Pv[(cbase + c * 16 + l16) * 8 + quad];
    short8 b1 = Pv[(cbase + c * 16 + l16) * 8 + quad + 4];
    f32x4 z = {0.f, 0.f, 0.f, 0.f};
    z = __builtin_amdgcn_mfma_f32_16x16x32_bf16(a0, b0, z, 0, 0, 0);
    z = __builtin_amdgcn_mfma_f32_16x16x32_bf16(a1, b1, z, 0, 0, 0);
    acc[c] = z;
  }

  float sr[4];
#pragma unroll
  for (int q = 0; q < 4; ++q) sr[q] = sq[rbase + quad * 4 + q];

#pragma unroll
  for (int c = 0; c < 4; ++c) {
    float sc = sq[cbase + c * 16 + l16];
#pragma unroll
    for (int q = 0; q < 4; ++q) {
      float d2 = sr[q] + sc - 2.f * acc[c][q];
      float dd = sqrtf(fmaxf(d2, 0.f));
      __hip_bfloat16 h = __float2bfloat16(dd);
      // C/D layout: row = quad*4+q, col = l16 (within the 16x16 tile)
      tile[(w * 16 + quad * 4 + q) * 72 + c * 16 + l16] = *(unsigned short*)&h;
    }
  }
  __syncthreads();

  // coalesced store: 512 chunks of 16B cover the 64x64 bf16 tile
  for (int i = t; i < 512; i += 256) {
    int row = i >> 3, cb8 = (i & 7) * 8;
    uint4 v = *(const uint4*)&tile[row * 72 + cb8];
    *(uint4*)&Dbf[(size_t)(blockIdx.y * 64 + row) * 4096 + cbase + cb8] = v;
  }

  // fused round-0 scan: thread t covers row r = t>>2, local cols
  // (t&3)*16 .. +15 (two aligned b128 LDS reads; bf16 bits order-preserving)
  {
    const int r = t >> 2, cseg = (t & 3) * 16;
    const int v = blockIdx.y * 64 + r;
    const uint4* lrow = (const uint4*)&tile[r * 72 + cseg];
    uint4 v0 = lrow[0], v1 = lrow[1];
    unsigned wv[16] = {v0.x & 0xFFFFu, v0.x >> 16, v0.y & 0xFFFFu, v0.y >> 16,
                       v0.z & 0xFFFFu, v0.z >> 16, v0.w & 0xFFFFu, v0.w >> 16,
                       v1.x & 0xFFFFu, v1.x >> 16, v1.y & 0xFFFFu, v1.y >> 16,
                       v1.z & 0xFFFFu, v1.z >> 16, v1.w & 0xFFFFu, v1.w >> 16};
    unsigned long long kmin = KINF;
#pragma unroll
    for (int e = 0; e < 16; ++e) {
      const int j = cbase + cseg + e;
      if (j != v) {
        unsigned ed = (v < j) ? (((unsigned)v << 12) | (unsigned)j)
                              : (((unsigned)j << 12) | (unsigned)v);
        unsigned long long key = ((unsigned long long)wv[e] << 24) | ed;
        kmin = key < kmin ? key : kmin;
      }
    }
#pragma unroll
    for (int m = 1; m < 4; m <<= 1) {
      unsigned long long o = __shfl_xor(kmin, m);
      kmin = o < kmin ? o : kmin;
    }
    if ((t & 3) == 0) atomicMin(&cheapest[v], kmin);
  }
}

// ---------------------------------------------------------------------------
// Boruvka: scan. 2048 blocks x 2 rows; whole block covers one row (thread t
// owns cols 16t..16t+15). comp16 (8 KB) read from L2 by every block.
// No-ops when done (cnt[1]). Only ever runs pre-compaction.
// ---------------------------------------------------------------------------
__global__ __launch_bounds__(256) void bor_scan(const unsigned short* Dbf,
                                                const unsigned short* comp16,
                                                int* parent,
                                                unsigned long long* cheapest,
                                                const unsigned* cnt) {
  if (cnt[1]) return;  // MST complete

  __shared__ unsigned long long redu[SCAN_ROWS][4];

  const int t = threadIdx.x;
  const int b = blockIdx.x;
  const int wave = t >> 6;
  const int gtid = b * 256 + t;
  const int vbase = b * SCAN_ROWS;

  if (gtid < NPTS) parent[gtid] = gtid;             // reset before hook

  // comp of this thread's 16 columns (32 B, L2-broadcast)
  const uint4* c16v = (const uint4*)comp16;
  uint4 c0 = c16v[2 * t], c1 = c16v[2 * t + 1];
  unsigned mc[16] = {c0.x & 0xFFFFu, c0.x >> 16, c0.y & 0xFFFFu, c0.y >> 16,
                     c0.z & 0xFFFFu, c0.z >> 16, c0.w & 0xFFFFu, c0.w >> 16,
                     c1.x & 0xFFFFu, c1.x >> 16, c1.y & 0xFFFFu, c1.y >> 16,
                     c1.z & 0xFFFFu, c1.z >> 16, c1.w & 0xFFFFu, c1.w >> 16};

  const uint4* rp = (const uint4*)(Dbf + (size_t)vbase * NPTS);
#pragma unroll
  for (int vv = 0; vv < SCAN_ROWS; ++vv) {
    const int v = vbase + vv;
    const unsigned cv = (unsigned)comp16[v];
    // row = 4096 shorts = 512 uint4; this thread covers cols 16t..16t+15
    uint4 a0 = rp[vv * 512 + 2 * t];
    uint4 a1 = rp[vv * 512 + 2 * t + 1];
    unsigned wv[16] = {a0.x & 0xFFFFu, a0.x >> 16, a0.y & 0xFFFFu, a0.y >> 16,
                       a0.z & 0xFFFFu, a0.z >> 16, a0.w & 0xFFFFu, a0.w >> 16,
                       a1.x & 0xFFFFu, a1.x >> 16, a1.y & 0xFFFFu, a1.y >> 16,
                       a1.z & 0xFFFFu, a1.z >> 16, a1.w & 0xFFFFu, a1.w >> 16};
    unsigned long long kmin = KINF;
#pragma unroll
    for (int e = 0; e < 16; ++e) {
      const int j = t * 16 + e;
      if (mc[e] != cv) {
        unsigned ed = (v < j) ? (((unsigned)v << 12) | (unsigned)j)
                              : (((unsigned)j << 12) | (unsigned)v);
        unsigned long long key = ((unsigned long long)wv[e] << 24) | ed;
        kmin = key < kmin ? key : kmin;
      }
    }
#pragma unroll
    for (int m = 1; m < 64; m <<= 1) {
      unsigned long long o = __shfl_xor(kmin, m);
      kmin = o < kmin ? o : kmin;
    }
    if ((t & 63) == 0) redu[vv][wave] = kmin;       // wave leader
  }
  __syncthreads();

  if (t < SCAN_ROWS) {
    unsigned long long k = redu[t][0];
    if (redu[t][1] < k) k = redu[t][1];
    if (redu[t][2] < k) k = redu[t][2];
    if (redu[t][3] < k) k = redu[t][3];
    if (k != KINF) atomicMin(&cheapest[(int)comp16[vbase + t]], k);
  }
}

// ---------------------------------------------------------------------------
// Boruvka: hook + relabel (single block).
// mode HOOK_FORCE_COMPACT (round 2): after relabel, assign compact ids.
// C <= 512 is guaranteed after 3 hook rounds (Boruvka halving), so no
// guard/fallback round is needed. M is pre-initialized by prep.
// ---------------------------------------------------------------------------
__global__ __launch_bounds__(1024) void bor_hook(int* comp,
                                                 unsigned short* comp16,
                                                 int* parent,
                                                 unsigned long long* cheapest,
                                                 float* edges, unsigned* cnt,
                                                 int mode) {
  if (cnt[1]) return;
  const int t = threadIdx.x;

  // hook roots along their min edge; record weight once per merge
  for (int i = t; i < NPTS; i += 1024) {
    if (comp[i] == i) {
      unsigned long long key = cheapest[i];
      if (key != KINF) {
        int mx = (int)(key & 0xFFFull);
        int mn = (int)((key >> 12) & 0xFFFull);
        int ca = comp[mn], cb = comp[mx];
        int u = (ca == i) ? cb : ca;
        bool mutual = (cheapest[u] == key);
        if (!mutual || i < u) {
          unsigned pos = atomicAdd(cnt, 1u);
          edges[pos] = bfbits2f((unsigned)(key >> 24));
        }
        if (!mutual || i > u) parent[i] = u;
      }
    }
  }
  __threadfence_block();
  __syncthreads();

  // relabel comp to new roots; reset cheapest
  for (int i = t; i < NPTS; i += 1024) {
    int r = comp[i], p;
    for (int it = 0; it < NPTS; ++it) {           // bounded walk (acyclic)
      p = parent[r];
      if (p == r) break;
      r = p;
    }
    comp[i] = r;
    comp16[i] = (unsigned short)r;
    cheapest[i] = KINF;
  }
  __threadfence_block();
  __syncthreads();

  if (mode == HOOK_FORCE_COMPACT) {
    // assign compact ids to roots (parent[] is free scratch now)
    for (int i = t; i < NPTS; i += 1024)
      if (comp[i] == i) parent[i] = (int)atomicAdd(&cnt[3], 1u);
    __syncthreads();
    for (int i = t; i < NPTS; i += 1024)
      comp16[i] = (unsigned short)parent[comp[i]];
  }
  if (t == 0 && cnt[0] >= (unsigned)(NPTS - 1)) cnt[1] = 1u;
}

// ---------------------------------------------------------------------------
// Project D onto the contracted graph: M[ci][cj] = min weight between
// compact comps ci,cj (ci,cj < 512). LDS pre-reduction (512-entry table per
// row) then <=2048 global atomicMin per block. Symmetry from D's symmetry.
// ---------------------------------------------------------------------------
__global__ __launch_bounds__(256) void bor_project(const unsigned short* Dbf,
                                                   const unsigned short* comp16,
                                                   unsigned* M,
                                                   const unsigned* cnt) {
  if (cnt[1]) return;

  __shared__ unsigned Mloc[SCAN_ROWS][CMAX];
  const int t = threadIdx.x;
  const int b = blockIdx.x;
  const int vbase = b * SCAN_ROWS;

  Mloc[0][t] = INV32;
  Mloc[0][t + 256] = INV32;
  Mloc[1][t] = INV32;
  Mloc[1][t + 256] = INV32;
  __syncthreads();

  const uint4* c16v = (const uint4*)comp16;
  uint4 c0 = c16v[2 * t], c1 = c16v[2 * t + 1];
  unsigned mc[16] = {c0.x & 0xFFFFu, c0.x >> 16, c0.y & 0xFFFFu, c0.y >> 16,
                     c0.z & 0xFFFFu, c0.z >> 16, c0.w & 0xFFFFu, c0.w >> 16,
                     c1.x & 0xFFFFu, c1.x >> 16, c1.y & 0xFFFFu, c1.y >> 16,
                     c1.z & 0xFFFFu, c1.z >> 16, c1.w & 0xFFFFu, c1.w >> 16};

  const uint4* rp = (const uint4*)(Dbf + (size_t)vbase * NPTS);
#pragma unroll
  for (int vv = 0; vv < SCAN_ROWS; ++vv) {
    const unsigned cv = (unsigned)comp16[vbase + vv];
    uint4 a0 = rp[vv * 512 + 2 * t];
    uint4 a1 = rp[vv * 512 + 2 * t + 1];
    unsigned wv[16] = {a0.x & 0xFFFFu, a0.x >> 16, a0.y & 0xFFFFu, a0.y >> 16,
                       a0.z & 0xFFFFu, a0.z >> 16, a0.w & 0xFFFFu, a0.w >> 16,
                       a1.x & 0xFFFFu, a1.x >> 16, a1.y & 0xFFFFu, a1.y >> 16,
                       a1.z & 0xFFFFu, a1.z >> 16, a1.w & 0xFFFFu, a1.w >> 16};
#pragma unroll
    for (int e = 0; e < 16; ++e)
      if (mc[e] != cv) atomicMin(&Mloc[vv][mc[e]], wv[e]);
  }
  __syncthreads();

  const unsigned cv0 = (unsigned)comp16[vbase];
  const unsigned cv1 = (unsigned)comp16[vbase + 1];
#pragma unroll
  for (int s = 0; s < 2; ++s) {
    const int col = t + 256 * s;
    unsigned x = Mloc[0][col];
    if (x != INV32) atomicMin(&M[cv0 * CMAX + col], x);
    unsigned y = Mloc[1][col];
    if (y != INV32) atomicMin(&M[cv1 * CMAX + col], y);
  }
}

// ---------------------------------------------------------------------------
// Finish MST on the contracted graph (C <= 512 comps): in-kernel Boruvka
// rounds with convergence early-exit. u64 keys: w16<<20 | lo<<10 | hi.
// ---------------------------------------------------------------------------
__global__ __launch_bounds__(1024) void bor_finish(const unsigned* M,
                                                   unsigned* cnt,
                                                   float* edges) {
  if (cnt[1]) return;

  __shared__ int comp2[CMAX];
  __shared__ int parent2[CMAX];
  __shared__ unsigned long long cheap2[CMAX];
  __shared__ int live;

  const int t = threadIdx.x;
  const int C = (int)cnt[3];
  if (t < CMAX) comp2[t] = t;
  __syncthreads();

  for (int round = 0; round < 10; ++round) {
    if (t < CMAX) cheap2[t] = KINF;
    if (t == 0) live = 0;
    __syncthreads();

    {
      const int c = t >> 1, q = t & 1;
      if (c < C) {
        const int cc = comp2[c];
        unsigned long long kmin = KINF;
        const uint4* Mr = (const uint4*)(M + c * CMAX + q * 256);
#pragma unroll 4
        for (int g = 0; g < 64; ++g) {
          uint4 m4 = Mr[g];
          const int j0 = q * 256 + g * 4;
          unsigned wj[4] = {m4.x, m4.y, m4.z, m4.w};
#pragma unroll
          for (int k = 0; k < 4; ++k) {
            int j = j0 + k;
            unsigned w = wj[k];
            if (w != INV32 && comp2[j] != cc) {
              int lo = c < j ? c : j, hi = c < j ? j : c;
              unsigned long long key = ((unsigned long long)w << 20) |
                                       ((unsigned)lo << 10) | (unsigned)hi;
              if (key < kmin) kmin = key;
            }
          }
        }
        if (kmin != KINF) atomicMin(&cheap2[cc], kmin);
      }
    }
    __syncthreads();

    if (t < CMAX) {
      parent2[t] = t;
      if (comp2[t] == t) {
        unsigned long long key = cheap2[t];
        if (key != KINF) {
          int hi = (int)(key & 0x3FFull);
          int lo = (int)((key >> 10) & 0x3FFull);
          int ca = comp2[lo], cb = comp2[hi];
          int u = (ca == t) ? cb : ca;
          bool mutual = (cheap2[u] == key);
          if (!mutual || t < u) {
            unsigned pos = atomicAdd(cnt, 1u);
            edges[pos] = bfbits2f((unsigned)(key >> 20));
          }
          if (!mutual || t > u) parent2[t] = u;
        }
      }
    }
    __syncthreads();

    if (t < CMAX) {
      int r = comp2[t], p;
      for (int it = 0; it < CMAX; ++it) {
        p = parent2[r];
        if (p == r) break;
        r = p;
      }
      comp2[t] = r;
      if (t < C && r != comp2[0]) live = 1;   // benign race, any-write
    }
    __syncthreads();
    if (!live) break;                          // uniform: all comps merged
  }
}

// ---------------------------------------------------------------------------
// Enumeration sort: block b computes ranks of edges[4b..4b+3] among all
// (value,idx) pairs (unique -> permutation) and writes out[rank] = value.
// edges[] (16 KB) L2-broadcast to 1024 blocks (was 4095). Dtype from cnt[2].
// ---------------------------------------------------------------------------
__global__ __launch_bounds__(256) void rank_sort(const float* edges,
                                                 const unsigned* cnt,
                                                 void* out) {
  __shared__ unsigned long long wred[4][2];
  const int b = blockIdx.x;          // pivots 4b..4b+3
  const int t = threadIdx.x;
  const int pbase = 4 * b;
  const float4* ev = (const float4*)edges;
  const float4 pvv = ev[b];          // the 4 pivot values (aligned)
  const float pv0 = pvv.x, pv1 = pvv.y, pv2 = pvv.z, pv3 = pvv.w;

  int c0 = 0, c1 = 0, c2 = 0, c3 = 0;
#pragma unroll
  for (int k = 0; k < 4; ++k) {
    float4 e = ev[t + 256 * k];
    int j = 4 * (t + 256 * k);
    float va[4] = {e.x, e.y, e.z, e.w};
#pragma unroll
    for (int m = 0; m < 4; ++m) {
      const float x = va[m];
      const int xi = j + m;
      c0 += (x < pv0 || (x == pv0 && xi < pbase + 0));
      c1 += (x < pv1 || (x == pv1 && xi < pbase + 1));
      c2 += (x < pv2 || (x == pv2 && xi < pbase + 2));
      c3 += (x < pv3 || (x == pv3 && xi < pbase + 3));
    }
  }

  // packed reductions: counts <= 4096 so 32-bit halves never interact
  unsigned long long p0 = (unsigned long long)(unsigned)c0 |
                          ((unsigned long long)(unsigned)c1 << 32);
  unsigned long long p1 = (unsigned long long)(unsigned)c2 |
                          ((unsigned long long)(unsigned)c3 << 32);
#pragma unroll
  for (int m = 1; m < 64; m <<= 1) {
    p0 += __shfl_xor(p0, m);
    p1 += __shfl_xor(p1, m);
  }
  if ((t & 63) == 0) { wred[t >> 6][0] = p0; wred[t >> 6][1] = p1; }
  __syncthreads();

  if (t == 0) {
    unsigned long long a = wred[0][0] + wred[1][0] + wred[2][0] + wred[3][0];
    unsigned long long d = wred[0][1] + wred[1][1] + wred[2][1] + wred[3][1];
    const int r[4] = {(int)(a & 0xFFFFFFFFull), (int)(a >> 32),
                      (int)(d & 0xFFFFFFFFull), (int)(d >> 32)};
    const float pv[4] = {pv0, pv1, pv2, pv3};
    const bool bf = cnt[2] != 0u;
#pragma unroll
    for (int p = 0; p < 4; ++p) {
      const int pidx = pbase + p;
      if (pidx < NPTS - 1) {     // pivot 4095 is the SENT sentinel
        if (bf) ((__hip_bfloat16*)out)[r[p]] = __float2bfloat16(pv[p]);
        else    ((float*)out)[r[p]] = pv[p];
      }
    }
  }
}

// ---------------------------------------------------------------------------
// Fallback kernels (verified R1/R4 path) for small-ws case.
// ---------------------------------------------------------------------------
__global__ __launch_bounds__(256) void dist_kernel(const void* pts_raw,
                                                   __hip_bfloat16* Dbf) {
  __shared__ float As[64 * 65];
  __shared__ float Bs[64 * 65];
  __shared__ float sqA[64];
  __shared__ float sqB[64];

  const int t = threadIdx.x;
  const int bx = blockIdx.x, by = blockIdx.y;
  const bool bf = data_is_bf16((const unsigned short*)pts_raw);
  const unsigned short* pu = (const unsigned short*)pts_raw;
  const float* pf = (const float*)pts_raw;

  for (int s = 0; s < 16; ++s) {
    int e = t + 256 * s;
    int r = e >> 6, c = e & 63;
    float av, bv;
    if (bf) {
      av = bfbits2f((unsigned int)pu[by * 4096 + e]);
      bv = bfbits2f((unsigned int)pu[bx * 4096 + e]);
    } else {
      av = pf[by * 4096 + e];
      bv = pf[bx * 4096 + e];
    }
    As[r * 65 + c] = av;
    Bs[r * 65 + c] = bv;
  }
  __syncthreads();

  if (t < 64) {
    float s = 0.f;
    for (int k = 0; k < 64; ++k) { float x = As[t * 65 + k]; s += x * x; }
    sqA[t] = s;
  } else if (t < 128) {
    int r = t - 64;
    float s = 0.f;
    for (int k = 0; k < 64; ++k) { float x = Bs[r * 65 + k]; s += x * x; }
    sqB[r] = s;
  }
  __syncthreads();

  const int tx = t & 15, ty = t >> 4;
  const int lr = ty * 4, lc = tx * 4;
  float acc[4][4] = {};
  for (int k = 0; k < 64; ++k) {
    float a[4], b[4];
#pragma unroll
    for (int q = 0; q < 4; ++q) a[q] = As[(lr + q) * 65 + k];
#pragma unroll
    for (int p = 0; p < 4; ++p) b[p] = Bs[(lc + p) * 65 + k];
#pragma unroll
    for (int q = 0; q < 4; ++q)
#pragma unroll
      for (int p = 0; p < 4; ++p) acc[q][p] += a[q] * b[p];
  }

#pragma unroll
  for (int q = 0; q < 4; ++q) {
    int gr = by * 64 + lr + q;
    float sa = sqA[lr + q];
#pragma unroll
    for (int p = 0; p < 4; ++p) {
      int gc = bx * 64 + lc + p;
      float d2 = sa + sqB[lc + p] - 2.f * acc[q][p];
      d2 = fmaxf(d2, 0.f);
      Dbf[(size_t)gr * 4096 + gc] = __float2bfloat16(sqrtf(d2));
    }
  }
}

__global__ __launch_bounds__(512) void prim_kernel(const unsigned short* probe,
                                                   const unsigned short* Dbf,
                                                   void* out) {
  __shared__ float len[NPTS];
  __shared__ float rv[2][8];
  __shared__ int ri[2][8];

  const int t = threadIdx.x;
  const bool bf_out = data_is_bf16(probe);

  float d[8];
  {
    const uint4* row0 = (const uint4*)(Dbf);
    uint4 v = row0[t];
    d[0] = bfbits2f(v.x & 0xffffu); d[1] = bfbits2f(v.x >> 16);
    d[2] = bfbits2f(v.y & 0xffffu); d[3] = bfbits2f(v.y >> 16);
    d[4] = bfbits2f(v.z & 0xffffu); d[5] = bfbits2f(v.z >> 16);
    d[6] = bfbits2f(v.w & 0xffffu); d[7] = bfbits2f(v.w >> 16);
    if (t == 0) d[0] = SENT;
  }

  float bv = SENT;
  int bi = 8 * t;
#pragma unroll
  for (int k = 0; k < 8; ++k)
    if (d[k] < bv) { bv = d[k]; bi = 8 * t + k; }

  for (int step = 0; step < NPTS - 1; ++step) {
    float v = bv;
    int idx = bi;
#pragma unroll
    for (int m = 1; m < 64; m <<= 1) {
      float ov = __shfl_xor(v, m);
      int oi = __shfl_xor(idx, m);
      if (ov < v) { v = ov; idx = oi; }
    }
    const int buf = step & 1;
    if ((t & 63) == 0) { rv[buf][t >> 6] = v; ri[buf][t >> 6] = idx; }
    __syncthreads();

    float w = rv[buf][0];
    int j = ri[buf][0];
#pragma unroll
    for (int u = 1; u < 8; ++u) {
      float uv = rv[buf][u];
      if (uv < w) { w = uv; j = ri[buf][u]; }
    }
    if (t == 0) len[step] = w;

    const uint4* row = (const uint4*)(Dbf + (size_t)j * NPTS);
    uint4 rw = row[t];
    float nd[8];
    nd[0] = bfbits2f(rw.x & 0xffffu); nd[1] = bfbits2f(rw.x >> 16);
    nd[2] = bfbits2f(rw.y & 0xffffu); nd[3] = bfbits2f(rw.y >> 16);
    nd[4] = bfbits2f(rw.z & 0xffffu); nd[5] = bfbits2f(rw.z >> 16);
    nd[6] = bfbits2f(rw.w & 0xffffu); nd[7] = bfbits2f(rw.w >> 16);

    bv = SENT;
    bi = 8 * t;
    const int base = 8 * t;
#pragma unroll
    for (int k = 0; k < 8; ++k) {
      float cur = d[k];
      float nn = fminf(cur, nd[k]);
      if (cur == SENT || base + k == j) nn = SENT;
      d[k] = nn;
      if (nn < bv) { bv = nn; bi = base + k; }
    }
  }

  if (t == 0) len[NPTS - 1] = SENT;
  __syncthreads();

  for (int k = 2; k <= NPTS; k <<= 1) {
    for (int jj = k >> 1; jj > 0; jj >>= 1) {
      for (int i = t; i < NPTS; i += 512) {
        int ixj = i ^ jj;
        if (ixj > i) {
          float a = len[i], b = len[ixj];
          bool up = ((i & k) == 0);
          if ((a > b) == up) { len[i] = b; len[ixj] = a; }
        }
      }
      __syncthreads();
    }
  }

  if (bf_out) {
    __hip_bfloat16* o = (__hip_bfloat16*)out;
    for (int i = t; i < NPTS - 1; i += 512) o[i] = __float2bfloat16(len[i]);
  } else {
    float* o = (float*)out;
    for (int i = t; i < NPTS - 1; i += 512) o[i] = len[i];
  }
}

extern "C" void kernel_launch(void* const* d_in, const int* in_sizes, int n_in,
                              void* d_out, int out_size, void* d_ws, size_t ws_size,
                              hipStream_t stream) {
  const void* pts = d_in[0];
  char* base = (char*)d_ws;
  __hip_bfloat16* Dbf = (__hip_bfloat16*)base;

  size_t off = 32ull << 20;                        // D: 32 MiB
  int* comp = (int*)(base + off);                  off += (size_t)NPTS * 4;
  int* parent = (int*)(base + off);                off += (size_t)NPTS * 4;
  unsigned long long* cheapest =
      (unsigned long long*)(base + off);           off += (size_t)NPTS * 8;
  float* edges = (float*)(base + off);             off += (size_t)NPTS * 4;
  unsigned* cnt = (unsigned*)(base + off);         off += 256;
  unsigned short* Pb = (unsigned short*)(base + off); off += (size_t)NPTS * 64 * 2;
  float* sq = (float*)(base + off);                off += (size_t)NPTS * 4;
  unsigned short* comp16 = (unsigned short*)(base + off); off += (size_t)NPTS * 2;
  unsigned* M = (unsigned*)(base + off);           off += (size_t)CMAX * CMAX * 4;

  if (ws_size >= off) {
    prep_kernel<<<1024, 256, 0, stream>>>(pts, Pb, sq, comp, comp16, parent,
                                          cheapest, edges, cnt, M);
    const unsigned short* Dus = (const unsigned short*)Dbf;
    dist_mfma<<<dim3(64, 64), 256, 0, stream>>>(Pb, sq, (unsigned short*)Dbf,
                                                cheapest);
    // hook round 0 (cheapest filled by the fused scan in dist_mfma)
    bor_hook<<<1, 1024, 0, stream>>>(comp, comp16, parent, cheapest, edges,
                                     cnt, HOOK_NORMAL);
    // round 1
    bor_scan<<<SCAN_BLOCKS, 256, 0, stream>>>(Dus, comp16, parent, cheapest,
                                              cnt);
    bor_hook<<<1, 1024, 0, stream>>>(comp, comp16, parent, cheapest, edges,
                                     cnt, HOOK_NORMAL);
    // round 2: C <= 512 guaranteed after this hook -> always compact
    bor_scan<<<SCAN_BLOCKS, 256, 0, stream>>>(Dus, comp16, parent, cheapest,
                                              cnt);
    bor_hook<<<1, 1024, 0, stream>>>(comp, comp16, parent, cheapest, edges,
                                     cnt, HOOK_FORCE_COMPACT);
    bor_project<<<SCAN_BLOCKS, 256, 0, stream>>>(Dus, comp16, M, cnt);
    bor_finish<<<1, 1024, 0, stream>>>(M, cnt, edges);
    rank_sort<<<NPTS / 4, 256, 0, stream>>>(edges, cnt, d_out);
  } else {
    dist_kernel<<<dim3(64, 64), 256, 0, stream>>>(pts, Dbf);
    prim_kernel<<<1, 512, 0, stream>>>((const unsigned short*)pts,
                                       (const unsigned short*)Dbf, d_out);
  }
}

// Round 2
// 189.677 us; speedup vs baseline: 1.0823x; 1.0740x over previous
//
#include <hip/hip_runtime.h>
#include <hip/hip_bf16.h>

// 0-dim Rips persistence deaths == Euclidean MST edge lengths.
// N=4096, DIM=64, output sorted ascending (4095 values).
//
// R12 (on verified R11): remove one full Boruvka round.
//  - Compact threshold raised 512 -> 1024. Boruvka halving guarantees
//    C <= 1024 after TWO hook rounds (4096->2048->1024), so hook1 always
//    compacts and scan2/hook2 are deleted. 10 -> 8 dispatches.
//  - M is 1024-wide (4 MB); prep inits it with one uint4 per thread
//    (1024x256 threads == exactly 512Ki uint4? no: 256Ki uint4 == 1Mi u32).
//  - bor_finish: u64 keys w16<<22 | lo<<11 | hi; 2 threads per row-half
//    with a c += 512 stride loop to cover C up to 1024.
//  - bor_project: LDS table [2][1024] (8 KB), 4 init/write segments.
// Everything else byte-identical to verified R11.
//
// Pipeline:
//   prep(+M init) ; dist_mfma(+scan0) ; hook0 ; scan1 ;
//   hook1(force-compact, C<=1024 guaranteed) ; bor_project ; bor_finish ;
//   rank_sort -> d_out
// Fallback: R1 Prim (+VALU dist) if ws too small.
//
// Fixed-floor note (R8-R11 evidence): top-5 dispatches are exclusively the
// harness's 256 MiB ws re-poison fills (47 us each, ~70% HBM peak); our
// dispatches sum to ~60-70 us; total includes a ~130-140 us floor outside
// kernel control.

#define NPTS 4096
#define SENT 1e30f
#define KINF 0xFFFFFFFFFFFFFFFFull
#define INV32 0xFFFFFFFFu
#define SCAN_ROWS 2
#define SCAN_BLOCKS (NPTS / SCAN_ROWS)
#define CMAX 1024         // compact component capacity (C <= 1024 after round 1)

// hook modes
#define HOOK_NORMAL 0
#define HOOK_FORCE_COMPACT 1

typedef short short8 __attribute__((ext_vector_type(8)));
typedef float f32x4 __attribute__((ext_vector_type(4)));

__device__ __forceinline__ float bfbits2f(unsigned int u16) {
  union { unsigned int u; float f; } c;
  c.u = u16 << 16;
  return c.f;
}

__device__ bool data_is_bf16(const unsigned short* p) {
  bool bf = true;
  for (int i = 0; i < 256; ++i) {
    float f = bfbits2f((unsigned int)p[i]);
    if (!(f > -1e6f && f < 1e6f)) bf = false;  // catches huge and NaN
  }
  return bf;
}

// ---------------------------------------------------------------------------
// prep (+ fused Boruvka init): one wave per point row. Convert to bf16 P,
// compute sq[]; init comp/comp16/parent/cheapest/edges-tail/cnt/M.
// Dtype probe: thread i checks element i (same 256 elems in every block),
// combined with __syncthreads_and -- no serial chain.
// M init: 1024 blocks x 256 threads x one uint4 = 256Ki uint4 = 4 MB.
// ---------------------------------------------------------------------------
__global__ __launch_bounds__(256) void prep_kernel(
    const void* pts_raw, unsigned short* Pb, float* sq, int* comp,
    unsigned short* comp16, int* parent, unsigned long long* cheapest,
    float* edges, unsigned* cnt, unsigned* M) {
  float pf = bfbits2f((unsigned int)((const unsigned short*)pts_raw)[threadIdx.x]);
  const bool bfs = (bool)__syncthreads_and((int)(pf > -1e6f && pf < 1e6f));

  const int g = blockIdx.x * 256 + threadIdx.x;
  if (g < NPTS) {
    comp[g] = g;
    comp16[g] = (unsigned short)g;
    parent[g] = g;               // hook 0 runs without a preceding bor_scan
    cheapest[g] = KINF;
  }
  {                              // 262144 threads x 16 B == CMAX*CMAX*4 B
    uint4 mi; mi.x = INV32; mi.y = INV32; mi.z = INV32; mi.w = INV32;
    ((uint4*)M)[g] = mi;
  }
  if (g == NPTS - 1) edges[NPTS - 1] = SENT;  // rank_sort tail (0xAA is neg!)
  if (g == 0) {
    cnt[0] = 0u;               // edge counter
    cnt[1] = 0u;               // done flag
    cnt[2] = bfs ? 1u : 0u;    // dtype flag
    cnt[3] = 0u;               // compact component count (0 = not compacted)
  }

  const int row = g >> 6;
  const int lane = threadIdx.x & 63;

  unsigned short ub;
  if (bfs) {
    ub = ((const unsigned short*)pts_raw)[row * 64 + lane];
  } else {
    __hip_bfloat16 h = __float2bfloat16(((const float*)pts_raw)[row * 64 + lane]);
    ub = *(unsigned short*)&h;
  }
  Pb[row * 64 + lane] = ub;

  float v = bfbits2f((unsigned int)ub);
  float s = v * v;
#pragma unroll
  for (int m = 1; m < 64; m <<= 1) s += __shfl_xor(s, m);
  if (lane == 0) sq[row] = s;
}

// ---------------------------------------------------------------------------
// dist via MFMA + fused round-0 scan. Block (bx,by) -> 64x64 tile; after the
// coalesced store, the LDS tile is reduced per-row (excluding the diagonal)
// and atomicMin'd into cheapest[] with the standard u64 edge key.
// ---------------------------------------------------------------------------
__global__ __launch_bounds__(256) void dist_mfma(const unsigned short* Pb,
                                                 const float* sq,
                                                 unsigned short* Dbf,
                                                 unsigned long long* cheapest) {
  __shared__ unsigned short tile[64 * 72];   // padded: stride 72 shorts

  const int t = threadIdx.x;
  const int w = t >> 6, lane = t & 63;
  const int quad = lane >> 4, l16 = lane & 15;
  const int rbase = blockIdx.y * 64 + w * 16;
  const int cbase = blockIdx.x * 64;

  const short8* Pv = (const short8*)Pb;      // row r = Pv[r*8 + k/8]
  short8 a0 = Pv[(rbase + l16) * 8 + quad];        // k = quad*8 .. +8
  short8 a1 = Pv[(rbase + l16) * 8 + quad + 4];    // k = 32+quad*8 .. +8

  f32x4 acc[4];
#pragma unroll
  for (int c = 0; c < 4; ++c) {
    short8 b0 = Pv[(cbase + c * 16 + l16) * 8 + quad];
    short8 b1 = Pv[(cbase + c * 16 + l16) * 8 + quad + 4];
    f32x4 z = {0.f, 0.f, 0.f, 0.f};
    z = __builtin_amdgcn_mfma_f32_16x16x32_bf16(a0, b0, z, 0, 0, 0);
    z = __builtin_amdgcn_mfma_f32_16x16x32_bf16(a1, b1, z, 0, 0, 0);
    acc[c] = z;
  }

  float sr[4];
#pragma unroll
  for (int q = 0; q < 4; ++q) sr[q] = sq[rbase + quad * 4 + q];

#pragma unroll
  for (int c = 0; c < 4; ++c) {
    float sc = sq[cbase + c * 16 + l16];
#pragma unroll
    for (int q = 0; q < 4; ++q) {
      float d2 = sr[q] + sc - 2.f * acc[c][q];
      float dd = sqrtf(fmaxf(d2, 0.f));
      __hip_bfloat16 h = __float2bfloat16(dd);
      // C/D layout: row = quad*4+q, col = l16 (within the 16x16 tile)
      tile[(w * 16 + quad * 4 + q) * 72 + c * 16 + l16] = *(unsigned short*)&h;
    }
  }
  __syncthreads();

  // coalesced store: 512 chunks of 16B cover the 64x64 bf16 tile
  for (int i = t; i < 512; i += 256) {
    int row = i >> 3, cb8 = (i & 7) * 8;
    uint4 v = *(const uint4*)&tile[row * 72 + cb8];
    *(uint4*)&Dbf[(size_t)(blockIdx.y * 64 + row) * 4096 + cbase + cb8] = v;
  }

  // fused round-0 scan: thread t covers row r = t>>2, local cols
  // (t&3)*16 .. +15 (two aligned b128 LDS reads; bf16 bits order-preserving)
  {
    const int r = t >> 2, cseg = (t & 3) * 16;
    const int v = blockIdx.y * 64 + r;
    const uint4* lrow = (const uint4*)&tile[r * 72 + cseg];
    uint4 v0 = lrow[0], v1 = lrow[1];
    unsigned wv[16] = {v0.x & 0xFFFFu, v0.x >> 16, v0.y & 0xFFFFu, v0.y >> 16,
                       v0.z & 0xFFFFu, v0.z >> 16, v0.w & 0xFFFFu, v0.w >> 16,
                       v1.x & 0xFFFFu, v1.x >> 16, v1.y & 0xFFFFu, v1.y >> 16,
                       v1.z & 0xFFFFu, v1.z >> 16, v1.w & 0xFFFFu, v1.w >> 16};
    unsigned long long kmin = KINF;
#pragma unroll
    for (int e = 0; e < 16; ++e) {
      const int j = cbase + cseg + e;
      if (j != v) {
        unsigned ed = (v < j) ? (((unsigned)v << 12) | (unsigned)j)
                              : (((unsigned)j << 12) | (unsigned)v);
        unsigned long long key = ((unsigned long long)wv[e] << 24) | ed;
        kmin = key < kmin ? key : kmin;
      }
    }
#pragma unroll
    for (int m = 1; m < 4; m <<= 1) {
      unsigned long long o = __shfl_xor(kmin, m);
      kmin = o < kmin ? o : kmin;
    }
    if ((t & 3) == 0) atomicMin(&cheapest[v], kmin);
  }
}

// ---------------------------------------------------------------------------
// Boruvka: scan. 2048 blocks x 2 rows; whole block covers one row (thread t
// owns cols 16t..16t+15). comp16 (8 KB) read from L2 by every block.
// No-ops when done (cnt[1]). Only ever runs pre-compaction.
// ---------------------------------------------------------------------------
__global__ __launch_bounds__(256) void bor_scan(const unsigned short* Dbf,
                                                const unsigned short* comp16,
                                                int* parent,
                                                unsigned long long* cheapest,
                                                const unsigned* cnt) {
  if (cnt[1]) return;  // MST complete

  __shared__ unsigned long long redu[SCAN_ROWS][4];

  const int t = threadIdx.x;
  const int b = blockIdx.x;
  const int wave = t >> 6;
  const int gtid = b * 256 + t;
  const int vbase = b * SCAN_ROWS;

  if (gtid < NPTS) parent[gtid] = gtid;             // reset before hook

  // comp of this thread's 16 columns (32 B, L2-broadcast)
  const uint4* c16v = (const uint4*)comp16;
  uint4 c0 = c16v[2 * t], c1 = c16v[2 * t + 1];
  unsigned mc[16] = {c0.x & 0xFFFFu, c0.x >> 16, c0.y & 0xFFFFu, c0.y >> 16,
                     c0.z & 0xFFFFu, c0.z >> 16, c0.w & 0xFFFFu, c0.w >> 16,
                     c1.x & 0xFFFFu, c1.x >> 16, c1.y & 0xFFFFu, c1.y >> 16,
                     c1.z & 0xFFFFu, c1.z >> 16, c1.w & 0xFFFFu, c1.w >> 16};

  const uint4* rp = (const uint4*)(Dbf + (size_t)vbase * NPTS);
#pragma unroll
  for (int vv = 0; vv < SCAN_ROWS; ++vv) {
    const int v = vbase + vv;
    const unsigned cv = (unsigned)comp16[v];
    // row = 4096 shorts = 512 uint4; this thread covers cols 16t..16t+15
    uint4 a0 = rp[vv * 512 + 2 * t];
    uint4 a1 = rp[vv * 512 + 2 * t + 1];
    unsigned wv[16] = {a0.x & 0xFFFFu, a0.x >> 16, a0.y & 0xFFFFu, a0.y >> 16,
                       a0.z & 0xFFFFu, a0.z >> 16, a0.w & 0xFFFFu, a0.w >> 16,
                       a1.x & 0xFFFFu, a1.x >> 16, a1.y & 0xFFFFu, a1.y >> 16,
                       a1.z & 0xFFFFu, a1.z >> 16, a1.w & 0xFFFFu, a1.w >> 16};
    unsigned long long kmin = KINF;
#pragma unroll
    for (int e = 0; e < 16; ++e) {
      const int j = t * 16 + e;
      if (mc[e] != cv) {
        unsigned ed = (v < j) ? (((unsigned)v << 12) | (unsigned)j)
                              : (((unsigned)j << 12) | (unsigned)v);
        unsigned long long key = ((unsigned long long)wv[e] << 24) | ed;
        kmin = key < kmin ? key : kmin;
      }
    }
#pragma unroll
    for (int m = 1; m < 64; m <<= 1) {
      unsigned long long o = __shfl_xor(kmin, m);
      kmin = o < kmin ? o : kmin;
    }
    if ((t & 63) == 0) redu[vv][wave] = kmin;       // wave leader
  }
  __syncthreads();

  if (t < SCAN_ROWS) {
    unsigned long long k = redu[t][0];
    if (redu[t][1] < k) k = redu[t][1];
    if (redu[t][2] < k) k = redu[t][2];
    if (redu[t][3] < k) k = redu[t][3];
    if (k != KINF) atomicMin(&cheapest[(int)comp16[vbase + t]], k);
  }
}

// ---------------------------------------------------------------------------
// Boruvka: hook + relabel (single block).
// mode HOOK_FORCE_COMPACT (round 1): after relabel, assign compact ids.
// C <= 1024 is guaranteed after 2 hook rounds (Boruvka halving:
// 4096 -> <=2048 -> <=1024), so no guard/fallback round is needed.
// M is pre-initialized by prep.
// ---------------------------------------------------------------------------
__global__ __launch_bounds__(1024) void bor_hook(int* comp,
                                                 unsigned short* comp16,
                                                 int* parent,
                                                 unsigned long long* cheapest,
                                                 float* edges, unsigned* cnt,
                                                 int mode) {
  if (cnt[1]) return;
  const int t = threadIdx.x;

  // hook roots along their min edge; record weight once per merge
  for (int i = t; i < NPTS; i += 1024) {
    if (comp[i] == i) {
      unsigned long long key = cheapest[i];
      if (key != KINF) {
        int mx = (int)(key & 0xFFFull);
        int mn = (int)((key >> 12) & 0xFFFull);
        int ca = comp[mn], cb = comp[mx];
        int u = (ca == i) ? cb : ca;
        bool mutual = (cheapest[u] == key);
        if (!mutual || i < u) {
          unsigned pos = atomicAdd(cnt, 1u);
          edges[pos] = bfbits2f((unsigned)(key >> 24));
        }
        if (!mutual || i > u) parent[i] = u;
      }
    }
  }
  __threadfence_block();
  __syncthreads();

  // relabel comp to new roots; reset cheapest
  for (int i = t; i < NPTS; i += 1024) {
    int r = comp[i], p;
    for (int it = 0; it < NPTS; ++it) {           // bounded walk (acyclic)
      p = parent[r];
      if (p == r) break;
      r = p;
    }
    comp[i] = r;
    comp16[i] = (unsigned short)r;
    cheapest[i] = KINF;
  }
  __threadfence_block();
  __syncthreads();

  if (mode == HOOK_FORCE_COMPACT) {
    // assign compact ids to roots (parent[] is free scratch now)
    for (int i = t; i < NPTS; i += 1024)
      if (comp[i] == i) parent[i] = (int)atomicAdd(&cnt[3], 1u);
    __syncthreads();
    for (int i = t; i < NPTS; i += 1024)
      comp16[i] = (unsigned short)parent[comp[i]];
  }
  if (t == 0 && cnt[0] >= (unsigned)(NPTS - 1)) cnt[1] = 1u;
}

// ---------------------------------------------------------------------------
// Project D onto the contracted graph: M[ci][cj] = min weight between
// compact comps ci,cj (ci,cj < 1024). LDS pre-reduction (1024-entry table
// per row, 8 KB total) then <=4096 global atomicMin per block (L2-resident
// M). Symmetry comes from D's symmetry.
// ---------------------------------------------------------------------------
__global__ __launch_bounds__(256) void bor_project(const unsigned short* Dbf,
                                                   const unsigned short* comp16,
                                                   unsigned* M,
                                                   const unsigned* cnt) {
  if (cnt[1]) return;

  __shared__ unsigned Mloc[SCAN_ROWS][CMAX];
  const int t = threadIdx.x;
  const int b = blockIdx.x;
  const int vbase = b * SCAN_ROWS;

#pragma unroll
  for (int s = 0; s < 4; ++s) {
    Mloc[0][t + 256 * s] = INV32;
    Mloc[1][t + 256 * s] = INV32;
  }
  __syncthreads();

  const uint4* c16v = (const uint4*)comp16;
  uint4 c0 = c16v[2 * t], c1 = c16v[2 * t + 1];
  unsigned mc[16] = {c0.x & 0xFFFFu, c0.x >> 16, c0.y & 0xFFFFu, c0.y >> 16,
                     c0.z & 0xFFFFu, c0.z >> 16, c0.w & 0xFFFFu, c0.w >> 16,
                     c1.x & 0xFFFFu, c1.x >> 16, c1.y & 0xFFFFu, c1.y >> 16,
                     c1.z & 0xFFFFu, c1.z >> 16, c1.w & 0xFFFFu, c1.w >> 16};

  const uint4* rp = (const uint4*)(Dbf + (size_t)vbase * NPTS);
#pragma unroll
  for (int vv = 0; vv < SCAN_ROWS; ++vv) {
    const unsigned cv = (unsigned)comp16[vbase + vv];
    uint4 a0 = rp[vv * 512 + 2 * t];
    uint4 a1 = rp[vv * 512 + 2 * t + 1];
    unsigned wv[16] = {a0.x & 0xFFFFu, a0.x >> 16, a0.y & 0xFFFFu, a0.y >> 16,
                       a0.z & 0xFFFFu, a0.z >> 16, a0.w & 0xFFFFu, a0.w >> 16,
                       a1.x & 0xFFFFu, a1.x >> 16, a1.y & 0xFFFFu, a1.y >> 16,
                       a1.z & 0xFFFFu, a1.z >> 16, a1.w & 0xFFFFu, a1.w >> 16};
#pragma unroll
    for (int e = 0; e < 16; ++e)
      if (mc[e] != cv) atomicMin(&Mloc[vv][mc[e]], wv[e]);
  }
  __syncthreads();

  const unsigned cv0 = (unsigned)comp16[vbase];
  const unsigned cv1 = (unsigned)comp16[vbase + 1];
#pragma unroll
  for (int s = 0; s < 4; ++s) {
    const int col = t + 256 * s;
    unsigned x = Mloc[0][col];
    if (x != INV32) atomicMin(&M[cv0 * CMAX + col], x);
    unsigned y = Mloc[1][col];
    if (y != INV32) atomicMin(&M[cv1 * CMAX + col], y);
  }
}

// ---------------------------------------------------------------------------
// Finish MST on the contracted graph (C <= 1024 comps): in-kernel Boruvka
// rounds with convergence early-exit. u64 keys: w16<<22 | lo<<11 | hi.
// Thread (t>>1, t&1) covers row-half; c += 512 stride covers C up to 1024.
// ---------------------------------------------------------------------------
__global__ __launch_bounds__(1024) void bor_finish(const unsigned* M,
                                                   unsigned* cnt,
                                                   float* edges) {
  if (cnt[1]) return;

  __shared__ int comp2[CMAX];
  __shared__ int parent2[CMAX];
  __shared__ unsigned long long cheap2[CMAX];
  __shared__ int live;

  const int t = threadIdx.x;         // blockDim == CMAX == 1024
  const int C = (int)cnt[3];
  comp2[t] = t;
  __syncthreads();

  for (int round = 0; round < 11; ++round) {
    cheap2[t] = KINF;
    if (t == 0) live = 0;
    __syncthreads();

    {
      const int q = t & 1;
      for (int c = t >> 1; c < C; c += 512) {
        const int cc = comp2[c];
        unsigned long long kmin = KINF;
        const uint4* Mr = (const uint4*)(M + c * CMAX + q * 512);
#pragma unroll 4
        for (int g = 0; g < 128; ++g) {
          uint4 m4 = Mr[g];
          const int j0 = q * 512 + g * 4;
          unsigned wj[4] = {m4.x, m4.y, m4.z, m4.w};
#pragma unroll
          for (int k = 0; k < 4; ++k) {
            int j = j0 + k;
            unsigned w = wj[k];
            if (w != INV32 && comp2[j] != cc) {
              int lo = c < j ? c : j, hi = c < j ? j : c;
              unsigned long long key = ((unsigned long long)w << 22) |
                                       ((unsigned)lo << 11) | (unsigned)hi;
              if (key < kmin) kmin = key;
            }
          }
        }
        if (kmin != KINF) atomicMin(&cheap2[cc], kmin);
      }
    }
    __syncthreads();

    {
      parent2[t] = t;
      if (comp2[t] == t) {
        unsigned long long key = cheap2[t];
        if (key != KINF) {
          int hi = (int)(key & 0x7FFull);
          int lo = (int)((key >> 11) & 0x7FFull);
          int ca = comp2[lo], cb = comp2[hi];
          int u = (ca == t) ? cb : ca;
          bool mutual = (cheap2[u] == key);
          if (!mutual || t < u) {
            unsigned pos = atomicAdd(cnt, 1u);
            edges[pos] = bfbits2f((unsigned)(key >> 22));
          }
          if (!mutual || t > u) parent2[t] = u;
        }
      }
    }
    __syncthreads();

    {
      int r = comp2[t], p;
      for (int it = 0; it < CMAX; ++it) {
        p = parent2[r];
        if (p == r) break;
        r = p;
      }
      comp2[t] = r;
      if (t < C && r != comp2[0]) live = 1;   // benign race, any-write
    }
    __syncthreads();
    if (!live) break;                          // uniform: all comps merged
  }
}

// ---------------------------------------------------------------------------
// Enumeration sort: block b computes ranks of edges[4b..4b+3] among all
// (value,idx) pairs (unique -> permutation) and writes out[rank] = value.
// edges[] (16 KB) L2-broadcast to 1024 blocks. Dtype from cnt[2].
// ---------------------------------------------------------------------------
__global__ __launch_bounds__(256) void rank_sort(const float* edges,
                                                 const unsigned* cnt,
                                                 void* out) {
  __shared__ unsigned long long wred[4][2];
  const int b = blockIdx.x;          // pivots 4b..4b+3
  const int t = threadIdx.x;
  const int pbase = 4 * b;
  const float4* ev = (const float4*)edges;
  const float4 pvv = ev[b];          // the 4 pivot values (aligned)
  const float pv0 = pvv.x, pv1 = pvv.y, pv2 = pvv.z, pv3 = pvv.w;

  int c0 = 0, c1 = 0, c2 = 0, c3 = 0;
#pragma unroll
  for (int k = 0; k < 4; ++k) {
    float4 e = ev[t + 256 * k];
    int j = 4 * (t + 256 * k);
    float va[4] = {e.x, e.y, e.z, e.w};
#pragma unroll
    for (int m = 0; m < 4; ++m) {
      const float x = va[m];
      const int xi = j + m;
      c0 += (x < pv0 || (x == pv0 && xi < pbase + 0));
      c1 += (x < pv1 || (x == pv1 && xi < pbase + 1));
      c2 += (x < pv2 || (x == pv2 && xi < pbase + 2));
      c3 += (x < pv3 || (x == pv3 && xi < pbase + 3));
    }
  }

  // packed reductions: counts <= 4096 so 32-bit halves never interact
  unsigned long long p0 = (unsigned long long)(unsigned)c0 |
                          ((unsigned long long)(unsigned)c1 << 32);
  unsigned long long p1 = (unsigned long long)(unsigned)c2 |
                          ((unsigned long long)(unsigned)c3 << 32);
#pragma unroll
  for (int m = 1; m < 64; m <<= 1) {
    p0 += __shfl_xor(p0, m);
    p1 += __shfl_xor(p1, m);
  }
  if ((t & 63) == 0) { wred[t >> 6][0] = p0; wred[t >> 6][1] = p1; }
  __syncthreads();

  if (t == 0) {
    unsigned long long a = wred[0][0] + wred[1][0] + wred[2][0] + wred[3][0];
    unsigned long long d = wred[0][1] + wred[1][1] + wred[2][1] + wred[3][1];
    const int r[4] = {(int)(a & 0xFFFFFFFFull), (int)(a >> 32),
                      (int)(d & 0xFFFFFFFFull), (int)(d >> 32)};
    const float pv[4] = {pv0, pv1, pv2, pv3};
    const bool bf = cnt[2] != 0u;
#pragma unroll
    for (int p = 0; p < 4; ++p) {
      const int pidx = pbase + p;
      if (pidx < NPTS - 1) {     // pivot 4095 is the SENT sentinel
        if (bf) ((__hip_bfloat16*)out)[r[p]] = __float2bfloat16(pv[p]);
        else    ((float*)out)[r[p]] = pv[p];
      }
    }
  }
}

// ---------------------------------------------------------------------------
// Fallback kernels (verified R1/R4 path) for small-ws case.
// ---------------------------------------------------------------------------
__global__ __launch_bounds__(256) void dist_kernel(const void* pts_raw,
                                                   __hip_bfloat16* Dbf) {
  __shared__ float As[64 * 65];
  __shared__ float Bs[64 * 65];
  __shared__ float sqA[64];
  __shared__ float sqB[64];

  const int t = threadIdx.x;
  const int bx = blockIdx.x, by = blockIdx.y;
  const bool bf = data_is_bf16((const unsigned short*)pts_raw);
  const unsigned short* pu = (const unsigned short*)pts_raw;
  const float* pf = (const float*)pts_raw;

  for (int s = 0; s < 16; ++s) {
    int e = t + 256 * s;
    int r = e >> 6, c = e & 63;
    float av, bv;
    if (bf) {
      av = bfbits2f((unsigned int)pu[by * 4096 + e]);
      bv = bfbits2f((unsigned int)pu[bx * 4096 + e]);
    } else {
      av = pf[by * 4096 + e];
      bv = pf[bx * 4096 + e];
    }
    As[r * 65 + c] = av;
    Bs[r * 65 + c] = bv;
  }
  __syncthreads();

  if (t < 64) {
    float s = 0.f;
    for (int k = 0; k < 64; ++k) { float x = As[t * 65 + k]; s += x * x; }
    sqA[t] = s;
  } else if (t < 128) {
    int r = t - 64;
    float s = 0.f;
    for (int k = 0; k < 64; ++k) { float x = Bs[r * 65 + k]; s += x * x; }
    sqB[r] = s;
  }
  __syncthreads();

  const int tx = t & 15, ty = t >> 4;
  const int lr = ty * 4, lc = tx * 4;
  float acc[4][4] = {};
  for (int k = 0; k < 64; ++k) {
    float a[4], b[4];
#pragma unroll
    for (int q = 0; q < 4; ++q) a[q] = As[(lr + q) * 65 + k];
#pragma unroll
    for (int p = 0; p < 4; ++p) b[p] = Bs[(lc + p) * 65 + k];
#pragma unroll
    for (int q = 0; q < 4; ++q)
#pragma unroll
      for (int p = 0; p < 4; ++p) acc[q][p] += a[q] * b[p];
  }

#pragma unroll
  for (int q = 0; q < 4; ++q) {
    int gr = by * 64 + lr + q;
    float sa = sqA[lr + q];
#pragma unroll
    for (int p = 0; p < 4; ++p) {
      int gc = bx * 64 + lc + p;
      float d2 = sa + sqB[lc + p] - 2.f * acc[q][p];
      d2 = fmaxf(d2, 0.f);
      Dbf[(size_t)gr * 4096 + gc] = __float2bfloat16(sqrtf(d2));
    }
  }
}

__global__ __launch_bounds__(512) void prim_kernel(const unsigned short* probe,
                                                   const unsigned short* Dbf,
                                                   void* out) {
  __shared__ float len[NPTS];
  __shared__ float rv[2][8];
  __shared__ int ri[2][8];

  const int t = threadIdx.x;
  const bool bf_out = data_is_bf16(probe);

  float d[8];
  {
    const uint4* row0 = (const uint4*)(Dbf);
    uint4 v = row0[t];
    d[0] = bfbits2f(v.x & 0xffffu); d[1] = bfbits2f(v.x >> 16);
    d[2] = bfbits2f(v.y & 0xffffu); d[3] = bfbits2f(v.y >> 16);
    d[4] = bfbits2f(v.z & 0xffffu); d[5] = bfbits2f(v.z >> 16);
    d[6] = bfbits2f(v.w & 0xffffu); d[7] = bfbits2f(v.w >> 16);
    if (t == 0) d[0] = SENT;
  }

  float bv = SENT;
  int bi = 8 * t;
#pragma unroll
  for (int k = 0; k < 8; ++k)
    if (d[k] < bv) { bv = d[k]; bi = 8 * t + k; }

  for (int step = 0; step < NPTS - 1; ++step) {
    float v = bv;
    int idx = bi;
#pragma unroll
    for (int m = 1; m < 64; m <<= 1) {
      float ov = __shfl_xor(v, m);
      int oi = __shfl_xor(idx, m);
      if (ov < v) { v = ov; idx = oi; }
    }
    const int buf = step & 1;
    if ((t & 63) == 0) { rv[buf][t >> 6] = v; ri[buf][t >> 6] = idx; }
    __syncthreads();

    float w = rv[buf][0];
    int j = ri[buf][0];
#pragma unroll
    for (int u = 1; u < 8; ++u) {
      float uv = rv[buf][u];
      if (uv < w) { w = uv; j = ri[buf][u]; }
    }
    if (t == 0) len[step] = w;

    const uint4* row = (const uint4*)(Dbf + (size_t)j * NPTS);
    uint4 rw = row[t];
    float nd[8];
    nd[0] = bfbits2f(rw.x & 0xffffu); nd[1] = bfbits2f(rw.x >> 16);
    nd[2] = bfbits2f(rw.y & 0xffffu); nd[3] = bfbits2f(rw.y >> 16);
    nd[4] = bfbits2f(rw.z & 0xffffu); nd[5] = bfbits2f(rw.z >> 16);
    nd[6] = bfbits2f(rw.w & 0xffffu); nd[7] = bfbits2f(rw.w >> 16);

    bv = SENT;
    bi = 8 * t;
    const int base = 8 * t;
#pragma unroll
    for (int k = 0; k < 8; ++k) {
      float cur = d[k];
      float nn = fminf(cur, nd[k]);
      if (cur == SENT || base + k == j) nn = SENT;
      d[k] = nn;
      if (nn < bv) { bv = nn; bi = base + k; }
    }
  }

  if (t == 0) len[NPTS - 1] = SENT;
  __syncthreads();

  for (int k = 2; k <= NPTS; k <<= 1) {
    for (int jj = k >> 1; jj > 0; jj >>= 1) {
      for (int i = t; i < NPTS; i += 512) {
        int ixj = i ^ jj;
        if (ixj > i) {
          float a = len[i], b = len[ixj];
          bool up = ((i & k) == 0);
          if ((a > b) == up) { len[i] = b; len[ixj] = a; }
        }
      }
      __syncthreads();
    }
  }

  if (bf_out) {
    __hip_bfloat16* o = (__hip_bfloat16*)out;
    for (int i = t; i < NPTS - 1; i += 512) o[i] = __float2bfloat16(len[i]);
  } else {
    float* o = (float*)out;
    for (int i = t; i < NPTS - 1; i += 512) o[i] = len[i];
  }
}

extern "C" void kernel_launch(void* const* d_in, const int* in_sizes, int n_in,
                              void* d_out, int out_size, void* d_ws, size_t ws_size,
                              hipStream_t stream) {
  const void* pts = d_in[0];
  char* base = (char*)d_ws;
  __hip_bfloat16* Dbf = (__hip_bfloat16*)base;

  size_t off = 32ull << 20;                        // D: 32 MiB
  int* comp = (int*)(base + off);                  off += (size_t)NPTS * 4;
  int* parent = (int*)(base + off);                off += (size_t)NPTS * 4;
  unsigned long long* cheapest =
      (unsigned long long*)(base + off);           off += (size_t)NPTS * 8;
  float* edges = (float*)(base + off);             off += (size_t)NPTS * 4;
  unsigned* cnt = (unsigned*)(base + off);         off += 256;
  unsigned short* Pb = (unsigned short*)(base + off); off += (size_t)NPTS * 64 * 2;
  float* sq = (float*)(base + off);                off += (size_t)NPTS * 4;
  unsigned short* comp16 = (unsigned short*)(base + off); off += (size_t)NPTS * 2;
  unsigned* M = (unsigned*)(base + off);           off += (size_t)CMAX * CMAX * 4;

  if (ws_size >= off) {
    prep_kernel<<<1024, 256, 0, stream>>>(pts, Pb, sq, comp, comp16, parent,
                                          cheapest, edges, cnt, M);
    const unsigned short* Dus = (const unsigned short*)Dbf;
    dist_mfma<<<dim3(64, 64), 256, 0, stream>>>(Pb, sq, (unsigned short*)Dbf,
                                                cheapest);
    // hook round 0 (cheapest filled by the fused scan in dist_mfma)
    bor_hook<<<1, 1024, 0, stream>>>(comp, comp16, parent, cheapest, edges,
                                     cnt, HOOK_NORMAL);
    // round 1: C <= 1024 guaranteed after this hook -> always compact
    bor_scan<<<SCAN_BLOCKS, 256, 0, stream>>>(Dus, comp16, parent, cheapest,
                                              cnt);
    bor_hook<<<1, 1024, 0, stream>>>(comp, comp16, parent, cheapest, edges,
                                     cnt, HOOK_FORCE_COMPACT);
    bor_project<<<SCAN_BLOCKS, 256, 0, stream>>>(Dus, comp16, M, cnt);
    bor_finish<<<1, 1024, 0, stream>>>(M, cnt, edges);
    rank_sort<<<NPTS / 4, 256, 0, stream>>>(edges, cnt, d_out);
  } else {
    dist_kernel<<<dim3(64, 64), 256, 0, stream>>>(pts, Dbf);
    prim_kernel<<<1, 512, 0, stream>>>((const unsigned short*)pts,
                                       (const unsigned short*)Dbf, d_out);
  }
}

// Round 3
// 164.457 us; speedup vs baseline: 1.2483x; 1.1534x over previous
//
#include <hip/hip_runtime.h>
#include <hip/hip_bf16.h>

// 0-dim Rips persistence deaths == Euclidean MST edge lengths.
// N=4096, DIM=64, output sorted ascending (4095 values).
//
// R13 (on verified R12): attack bor_finish (rocprof: 47.4 us, ~98% L2-latency
// stalled, single block scanning C rows x 1024 cols x ~10 rounds).
//  - Col-bound finish's M scan to C (cols >= C are INV32, never written):
//    ~2x less traffic at typical C~500.
//  - 4-way row split (work-items = 4*C quarters, stride-1024 loop): shorter
//    dependent-load chains per thread, better latency overlap.
//  - bor_project now seeds the contracted round 0: per-row canonical-key
//    (w<<22|lo<<11|hi, compact ids) block reduction folded into its existing
//    Mloc write-out, one u64 atomicMin per row into global cheapM[C].
//    bor_finish round 0 skips its M scan (the most expensive round: all C
//    comps alive) and hooks directly from cheapM.
// Everything else byte-identical to verified R12.
//
// Pipeline:
//   prep(+M/cheapM init) ; dist_mfma(+scan0) ; hook0 ; scan1 ;
//   hook1(force-compact, C<=1024 guaranteed) ; bor_project(+round0 seed) ;
//   bor_finish ; rank_sort -> d_out
// Fallback: R1 Prim (+VALU dist) if ws too small.
//
// Fixed-floor note: harness's 256 MiB ws re-poison fills are 47 us each at
// ~70% HBM peak -- outside kernel control.

#define NPTS 4096
#define SENT 1e30f
#define KINF 0xFFFFFFFFFFFFFFFFull
#define INV32 0xFFFFFFFFu
#define SCAN_ROWS 2
#define SCAN_BLOCKS (NPTS / SCAN_ROWS)
#define CMAX 1024         // compact component capacity (C <= 1024 after round 1)

// hook modes
#define HOOK_NORMAL 0
#define HOOK_FORCE_COMPACT 1

typedef short short8 __attribute__((ext_vector_type(8)));
typedef float f32x4 __attribute__((ext_vector_type(4)));

__device__ __forceinline__ float bfbits2f(unsigned int u16) {
  union { unsigned int u; float f; } c;
  c.u = u16 << 16;
  return c.f;
}

__device__ bool data_is_bf16(const unsigned short* p) {
  bool bf = true;
  for (int i = 0; i < 256; ++i) {
    float f = bfbits2f((unsigned int)p[i]);
    if (!(f > -1e6f && f < 1e6f)) bf = false;  // catches huge and NaN
  }
  return bf;
}

// ---------------------------------------------------------------------------
// prep (+ fused Boruvka init): one wave per point row. Convert to bf16 P,
// compute sq[]; init comp/comp16/parent/cheapest/edges-tail/cnt/M/cheapM.
// Dtype probe: thread i checks element i (same 256 elems in every block),
// combined with __syncthreads_and -- no serial chain.
// M init: 1024 blocks x 256 threads x one uint4 = 256Ki uint4 = 4 MB.
// ---------------------------------------------------------------------------
__global__ __launch_bounds__(256) void prep_kernel(
    const void* pts_raw, unsigned short* Pb, float* sq, int* comp,
    unsigned short* comp16, int* parent, unsigned long long* cheapest,
    float* edges, unsigned* cnt, unsigned* M, unsigned long long* cheapM) {
  float pf = bfbits2f((unsigned int)((const unsigned short*)pts_raw)[threadIdx.x]);
  const bool bfs = (bool)__syncthreads_and((int)(pf > -1e6f && pf < 1e6f));

  const int g = blockIdx.x * 256 + threadIdx.x;
  if (g < NPTS) {
    comp[g] = g;
    comp16[g] = (unsigned short)g;
    parent[g] = g;               // hook 0 runs without a preceding bor_scan
    cheapest[g] = KINF;
  }
  if (g < CMAX) cheapM[g] = KINF;
  {                              // 262144 threads x 16 B == CMAX*CMAX*4 B
    uint4 mi; mi.x = INV32; mi.y = INV32; mi.z = INV32; mi.w = INV32;
    ((uint4*)M)[g] = mi;
  }
  if (g == NPTS - 1) edges[NPTS - 1] = SENT;  // rank_sort tail (0xAA is neg!)
  if (g == 0) {
    cnt[0] = 0u;               // edge counter
    cnt[1] = 0u;               // done flag
    cnt[2] = bfs ? 1u : 0u;    // dtype flag
    cnt[3] = 0u;               // compact component count (0 = not compacted)
  }

  const int row = g >> 6;
  const int lane = threadIdx.x & 63;

  unsigned short ub;
  if (bfs) {
    ub = ((const unsigned short*)pts_raw)[row * 64 + lane];
  } else {
    __hip_bfloat16 h = __float2bfloat16(((const float*)pts_raw)[row * 64 + lane]);
    ub = *(unsigned short*)&h;
  }
  Pb[row * 64 + lane] = ub;

  float v = bfbits2f((unsigned int)ub);
  float s = v * v;
#pragma unroll
  for (int m = 1; m < 64; m <<= 1) s += __shfl_xor(s, m);
  if (lane == 0) sq[row] = s;
}

// ---------------------------------------------------------------------------
// dist via MFMA + fused round-0 scan. Block (bx,by) -> 64x64 tile; after the
// coalesced store, the LDS tile is reduced per-row (excluding the diagonal)
// and atomicMin'd into cheapest[] with the standard u64 edge key.
// ---------------------------------------------------------------------------
__global__ __launch_bounds__(256) void dist_mfma(const unsigned short* Pb,
                                                 const float* sq,
                                                 unsigned short* Dbf,
                                                 unsigned long long* cheapest) {
  __shared__ unsigned short tile[64 * 72];   // padded: stride 72 shorts

  const int t = threadIdx.x;
  const int w = t >> 6, lane = t & 63;
  const int quad = lane >> 4, l16 = lane & 15;
  const int rbase = blockIdx.y * 64 + w * 16;
  const int cbase = blockIdx.x * 64;

  const short8* Pv = (const short8*)Pb;      // row r = Pv[r*8 + k/8]
  short8 a0 = Pv[(rbase + l16) * 8 + quad];        // k = quad*8 .. +8
  short8 a1 = Pv[(rbase + l16) * 8 + quad + 4];    // k = 32+quad*8 .. +8

  f32x4 acc[4];
#pragma unroll
  for (int c = 0; c < 4; ++c) {
    short8 b0 = Pv[(cbase + c * 16 + l16) * 8 + quad];
    short8 b1 = Pv[(cbase + c * 16 + l16) * 8 + quad + 4];
    f32x4 z = {0.f, 0.f, 0.f, 0.f};
    z = __builtin_amdgcn_mfma_f32_16x16x32_bf16(a0, b0, z, 0, 0, 0);
    z = __builtin_amdgcn_mfma_f32_16x16x32_bf16(a1, b1, z, 0, 0, 0);
    acc[c] = z;
  }

  float sr[4];
#pragma unroll
  for (int q = 0; q < 4; ++q) sr[q] = sq[rbase + quad * 4 + q];

#pragma unroll
  for (int c = 0; c < 4; ++c) {
    float sc = sq[cbase + c * 16 + l16];
#pragma unroll
    for (int q = 0; q < 4; ++q) {
      float d2 = sr[q] + sc - 2.f * acc[c][q];
      float dd = sqrtf(fmaxf(d2, 0.f));
      __hip_bfloat16 h = __float2bfloat16(dd);
      // C/D layout: row = quad*4+q, col = l16 (within the 16x16 tile)
      tile[(w * 16 + quad * 4 + q) * 72 + c * 16 + l16] = *(unsigned short*)&h;
    }
  }
  __syncthreads();

  // coalesced store: 512 chunks of 16B cover the 64x64 bf16 tile
  for (int i = t; i < 512; i += 256) {
    int row = i >> 3, cb8 = (i & 7) * 8;
    uint4 v = *(const uint4*)&tile[row * 72 + cb8];
    *(uint4*)&Dbf[(size_t)(blockIdx.y * 64 + row) * 4096 + cbase + cb8] = v;
  }

  // fused round-0 scan: thread t covers row r = t>>2, local cols
  // (t&3)*16 .. +15 (two aligned b128 LDS reads; bf16 bits order-preserving)
  {
    const int r = t >> 2, cseg = (t & 3) * 16;
    const int v = blockIdx.y * 64 + r;
    const uint4* lrow = (const uint4*)&tile[r * 72 + cseg];
    uint4 v0 = lrow[0], v1 = lrow[1];
    unsigned wv[16] = {v0.x & 0xFFFFu, v0.x >> 16, v0.y & 0xFFFFu, v0.y >> 16,
                       v0.z & 0xFFFFu, v0.z >> 16, v0.w & 0xFFFFu, v0.w >> 16,
                       v1.x & 0xFFFFu, v1.x >> 16, v1.y & 0xFFFFu, v1.y >> 16,
                       v1.z & 0xFFFFu, v1.z >> 16, v1.w & 0xFFFFu, v1.w >> 16};
    unsigned long long kmin = KINF;
#pragma unroll
    for (int e = 0; e < 16; ++e) {
      const int j = cbase + cseg + e;
      if (j != v) {
        unsigned ed = (v < j) ? (((unsigned)v << 12) | (unsigned)j)
                              : (((unsigned)j << 12) | (unsigned)v);
        unsigned long long key = ((unsigned long long)wv[e] << 24) | ed;
        kmin = key < kmin ? key : kmin;
      }
    }
#pragma unroll
    for (int m = 1; m < 4; m <<= 1) {
      unsigned long long o = __shfl_xor(kmin, m);
      kmin = o < kmin ? o : kmin;
    }
    if ((t & 3) == 0) atomicMin(&cheapest[v], kmin);
  }
}

// ---------------------------------------------------------------------------
// Boruvka: scan. 2048 blocks x 2 rows; whole block covers one row (thread t
// owns cols 16t..16t+15). comp16 (8 KB) read from L2 by every block.
// No-ops when done (cnt[1]). Only ever runs pre-compaction.
// ---------------------------------------------------------------------------
__global__ __launch_bounds__(256) void bor_scan(const unsigned short* Dbf,
                                                const unsigned short* comp16,
                                                int* parent,
                                                unsigned long long* cheapest,
                                                const unsigned* cnt) {
  if (cnt[1]) return;  // MST complete

  __shared__ unsigned long long redu[SCAN_ROWS][4];

  const int t = threadIdx.x;
  const int b = blockIdx.x;
  const int wave = t >> 6;
  const int gtid = b * 256 + t;
  const int vbase = b * SCAN_ROWS;

  if (gtid < NPTS) parent[gtid] = gtid;             // reset before hook

  // comp of this thread's 16 columns (32 B, L2-broadcast)
  const uint4* c16v = (const uint4*)comp16;
  uint4 c0 = c16v[2 * t], c1 = c16v[2 * t + 1];
  unsigned mc[16] = {c0.x & 0xFFFFu, c0.x >> 16, c0.y & 0xFFFFu, c0.y >> 16,
                     c0.z & 0xFFFFu, c0.z >> 16, c0.w & 0xFFFFu, c0.w >> 16,
                     c1.x & 0xFFFFu, c1.x >> 16, c1.y & 0xFFFFu, c1.y >> 16,
                     c1.z & 0xFFFFu, c1.z >> 16, c1.w & 0xFFFFu, c1.w >> 16};

  const uint4* rp = (const uint4*)(Dbf + (size_t)vbase * NPTS);
#pragma unroll
  for (int vv = 0; vv < SCAN_ROWS; ++vv) {
    const int v = vbase + vv;
    const unsigned cv = (unsigned)comp16[v];
    // row = 4096 shorts = 512 uint4; this thread covers cols 16t..16t+15
    uint4 a0 = rp[vv * 512 + 2 * t];
    uint4 a1 = rp[vv * 512 + 2 * t + 1];
    unsigned wv[16] = {a0.x & 0xFFFFu, a0.x >> 16, a0.y & 0xFFFFu, a0.y >> 16,
                       a0.z & 0xFFFFu, a0.z >> 16, a0.w & 0xFFFFu, a0.w >> 16,
                       a1.x & 0xFFFFu, a1.x >> 16, a1.y & 0xFFFFu, a1.y >> 16,
                       a1.z & 0xFFFFu, a1.z >> 16, a1.w & 0xFFFFu, a1.w >> 16};
    unsigned long long kmin = KINF;
#pragma unroll
    for (int e = 0; e < 16; ++e) {
      const int j = t * 16 + e;
      if (mc[e] != cv) {
        unsigned ed = (v < j) ? (((unsigned)v << 12) | (unsigned)j)
                              : (((unsigned)j << 12) | (unsigned)v);
        unsigned long long key = ((unsigned long long)wv[e] << 24) | ed;
        kmin = key < kmin ? key : kmin;
      }
    }
#pragma unroll
    for (int m = 1; m < 64; m <<= 1) {
      unsigned long long o = __shfl_xor(kmin, m);
      kmin = o < kmin ? o : kmin;
    }
    if ((t & 63) == 0) redu[vv][wave] = kmin;       // wave leader
  }
  __syncthreads();

  if (t < SCAN_ROWS) {
    unsigned long long k = redu[t][0];
    if (redu[t][1] < k) k = redu[t][1];
    if (redu[t][2] < k) k = redu[t][2];
    if (redu[t][3] < k) k = redu[t][3];
    if (k != KINF) atomicMin(&cheapest[(int)comp16[vbase + t]], k);
  }
}

// ---------------------------------------------------------------------------
// Boruvka: hook + relabel (single block).
// mode HOOK_FORCE_COMPACT (round 1): after relabel, assign compact ids.
// C <= 1024 is guaranteed after 2 hook rounds (Boruvka halving:
// 4096 -> <=2048 -> <=1024), so no guard/fallback round is needed.
// M is pre-initialized by prep.
// ---------------------------------------------------------------------------
__global__ __launch_bounds__(1024) void bor_hook(int* comp,
                                                 unsigned short* comp16,
                                                 int* parent,
                                                 unsigned long long* cheapest,
                                                 float* edges, unsigned* cnt,
                                                 int mode) {
  if (cnt[1]) return;
  const int t = threadIdx.x;

  // hook roots along their min edge; record weight once per merge
  for (int i = t; i < NPTS; i += 1024) {
    if (comp[i] == i) {
      unsigned long long key = cheapest[i];
      if (key != KINF) {
        int mx = (int)(key & 0xFFFull);
        int mn = (int)((key >> 12) & 0xFFFull);
        int ca = comp[mn], cb = comp[mx];
        int u = (ca == i) ? cb : ca;
        bool mutual = (cheapest[u] == key);
        if (!mutual || i < u) {
          unsigned pos = atomicAdd(cnt, 1u);
          edges[pos] = bfbits2f((unsigned)(key >> 24));
        }
        if (!mutual || i > u) parent[i] = u;
      }
    }
  }
  __threadfence_block();
  __syncthreads();

  // relabel comp to new roots; reset cheapest
  for (int i = t; i < NPTS; i += 1024) {
    int r = comp[i], p;
    for (int it = 0; it < NPTS; ++it) {           // bounded walk (acyclic)
      p = parent[r];
      if (p == r) break;
      r = p;
    }
    comp[i] = r;
    comp16[i] = (unsigned short)r;
    cheapest[i] = KINF;
  }
  __threadfence_block();
  __syncthreads();

  if (mode == HOOK_FORCE_COMPACT) {
    // assign compact ids to roots (parent[] is free scratch now)
    for (int i = t; i < NPTS; i += 1024)
      if (comp[i] == i) parent[i] = (int)atomicAdd(&cnt[3], 1u);
    __syncthreads();
    for (int i = t; i < NPTS; i += 1024)
      comp16[i] = (unsigned short)parent[comp[i]];
  }
  if (t == 0 && cnt[0] >= (unsigned)(NPTS - 1)) cnt[1] = 1u;
}

// ---------------------------------------------------------------------------
// Project D onto the contracted graph: M[ci][cj] = min weight between
// compact comps ci,cj (ci,cj < 1024). LDS pre-reduction (1024-entry table
// per row, 8 KB total) then <=4096 global atomicMin per block (L2-resident
// M). Symmetry comes from D's symmetry.
// Fused contracted round-0 seed: per-row canonical-key min (w<<22|lo<<11|hi,
// compact ids) block-reduced and atomicMin'd into cheapM[row_comp] -- lets
// bor_finish skip its most expensive scan round.
// ---------------------------------------------------------------------------
__global__ __launch_bounds__(256) void bor_project(const unsigned short* Dbf,
                                                   const unsigned short* comp16,
                                                   unsigned* M,
                                                   const unsigned* cnt,
                                                   unsigned long long* cheapM) {
  if (cnt[1]) return;

  __shared__ unsigned Mloc[SCAN_ROWS][CMAX];
  __shared__ unsigned long long redc[SCAN_ROWS][4];
  const int t = threadIdx.x;
  const int b = blockIdx.x;
  const int vbase = b * SCAN_ROWS;

#pragma unroll
  for (int s = 0; s < 4; ++s) {
    Mloc[0][t + 256 * s] = INV32;
    Mloc[1][t + 256 * s] = INV32;
  }
  __syncthreads();

  const uint4* c16v = (const uint4*)comp16;
  uint4 c0 = c16v[2 * t], c1 = c16v[2 * t + 1];
  unsigned mc[16] = {c0.x & 0xFFFFu, c0.x >> 16, c0.y & 0xFFFFu, c0.y >> 16,
                     c0.z & 0xFFFFu, c0.z >> 16, c0.w & 0xFFFFu, c0.w >> 16,
                     c1.x & 0xFFFFu, c1.x >> 16, c1.y & 0xFFFFu, c1.y >> 16,
                     c1.z & 0xFFFFu, c1.z >> 16, c1.w & 0xFFFFu, c1.w >> 16};

  const uint4* rp = (const uint4*)(Dbf + (size_t)vbase * NPTS);
#pragma unroll
  for (int vv = 0; vv < SCAN_ROWS; ++vv) {
    const unsigned cv = (unsigned)comp16[vbase + vv];
    uint4 a0 = rp[vv * 512 + 2 * t];
    uint4 a1 = rp[vv * 512 + 2 * t + 1];
    unsigned wv[16] = {a0.x & 0xFFFFu, a0.x >> 16, a0.y & 0xFFFFu, a0.y >> 16,
                       a0.z & 0xFFFFu, a0.z >> 16, a0.w & 0xFFFFu, a0.w >> 16,
                       a1.x & 0xFFFFu, a1.x >> 16, a1.y & 0xFFFFu, a1.y >> 16,
                       a1.z & 0xFFFFu, a1.z >> 16, a1.w & 0xFFFFu, a1.w >> 16};
#pragma unroll
    for (int e = 0; e < 16; ++e)
      if (mc[e] != cv) atomicMin(&Mloc[vv][mc[e]], wv[e]);
  }
  __syncthreads();

  const unsigned cv0 = (unsigned)comp16[vbase];
  const unsigned cv1 = (unsigned)comp16[vbase + 1];
  unsigned long long k0 = KINF, k1 = KINF;
#pragma unroll
  for (int s = 0; s < 4; ++s) {
    const unsigned col = (unsigned)(t + 256 * s);
    unsigned x = Mloc[0][col];
    if (x != INV32) {
      atomicMin(&M[cv0 * CMAX + col], x);
      unsigned lo = cv0 < col ? cv0 : col, hi = cv0 < col ? col : cv0;
      unsigned long long key =
          ((unsigned long long)x << 22) | (lo << 11) | hi;
      if (key < k0) k0 = key;
    }
    unsigned y = Mloc[1][col];
    if (y != INV32) {
      atomicMin(&M[cv1 * CMAX + col], y);
      unsigned lo = cv1 < col ? cv1 : col, hi = cv1 < col ? col : cv1;
      unsigned long long key =
          ((unsigned long long)y << 22) | (lo << 11) | hi;
      if (key < k1) k1 = key;
    }
  }

  // block-reduce the two per-row canonical-key minima -> cheapM
#pragma unroll
  for (int m = 1; m < 64; m <<= 1) {
    unsigned long long o0 = __shfl_xor(k0, m);
    if (o0 < k0) k0 = o0;
    unsigned long long o1 = __shfl_xor(k1, m);
    if (o1 < k1) k1 = o1;
  }
  if ((t & 63) == 0) { redc[0][t >> 6] = k0; redc[1][t >> 6] = k1; }
  __syncthreads();
  if (t < SCAN_ROWS) {
    unsigned long long k = redc[t][0];
    if (redc[t][1] < k) k = redc[t][1];
    if (redc[t][2] < k) k = redc[t][2];
    if (redc[t][3] < k) k = redc[t][3];
    if (k != KINF)
      atomicMin(&cheapM[(int)comp16[vbase + t]], k);
  }
}

// ---------------------------------------------------------------------------
// Finish MST on the contracted graph (C <= 1024 comps): in-kernel Boruvka
// rounds with convergence early-exit. u64 keys: w16<<22 | lo<<11 | hi.
// Round 0 is seeded from cheapM (computed grid-parallel in bor_project) --
// no M scan. Rounds >= 1 scan M col-bounded to C with a 4-way row split
// (work-items = 4*C quarters) for shorter dependent-load chains.
// ---------------------------------------------------------------------------
__global__ __launch_bounds__(1024) void bor_finish(const unsigned* M,
                                                   unsigned* cnt,
                                                   float* edges,
                                                   const unsigned long long* cheapM) {
  if (cnt[1]) return;

  __shared__ int comp2[CMAX];
  __shared__ int parent2[CMAX];
  __shared__ unsigned long long cheap2[CMAX];
  __shared__ int live;

  const int t = threadIdx.x;         // blockDim == CMAX == 1024
  const int C = (int)cnt[3];
  comp2[t] = t;
  __syncthreads();

  for (int round = 0; round < 11; ++round) {
    cheap2[t] = KINF;
    if (t == 0) live = 0;
    __syncthreads();

    if (round == 0) {
      // seeded grid-parallel by bor_project; one writer per slot
      if (t < C) cheap2[t] = cheapM[t];
    } else {
      const int Cu4 = (C + 3) >> 2;     // uint4s of real data per row
      const int Q4 = (Cu4 + 3) >> 2;    // uint4s per quarter
      for (int item = t; item < 4 * C; item += 1024) {
        const int c = item >> 2, q = item & 3;
        const int cc = comp2[c];
        const int lo4 = q * Q4;
        int hi4 = lo4 + Q4; if (hi4 > Cu4) hi4 = Cu4;
        unsigned long long kmin = KINF;
        const uint4* Mr = (const uint4*)(M + c * CMAX);
        for (int u = lo4; u < hi4; ++u) {
          uint4 m4 = Mr[u];
          const int j0 = u * 4;
          unsigned wj[4] = {m4.x, m4.y, m4.z, m4.w};
#pragma unroll
          for (int k = 0; k < 4; ++k) {
            int j = j0 + k;
            unsigned w = wj[k];
            // cols >= C are INV32 (never written) -> filtered by w check
            if (w != INV32 && comp2[j] != cc) {
              int lo = c < j ? c : j, hi = c < j ? j : c;
              unsigned long long key = ((unsigned long long)w << 22) |
                                       ((unsigned)lo << 11) | (unsigned)hi;
              if (key < kmin) kmin = key;
            }
          }
        }
        if (kmin != KINF) atomicMin(&cheap2[cc], kmin);
      }
    }
    __syncthreads();

    {
      parent2[t] = t;
      if (comp2[t] == t) {
        unsigned long long key = cheap2[t];
        if (key != KINF) {
          int hi = (int)(key & 0x7FFull);
          int lo = (int)((key >> 11) & 0x7FFull);
          int ca = comp2[lo], cb = comp2[hi];
          int u = (ca == t) ? cb : ca;
          bool mutual = (cheap2[u] == key);
          if (!mutual || t < u) {
            unsigned pos = atomicAdd(cnt, 1u);
            edges[pos] = bfbits2f((unsigned)(key >> 22));
          }
          if (!mutual || t > u) parent2[t] = u;
        }
      }
    }
    __syncthreads();

    {
      int r = comp2[t], p;
      for (int it = 0; it < CMAX; ++it) {
        p = parent2[r];
        if (p == r) break;
        r = p;
      }
      comp2[t] = r;
      if (t < C && r != comp2[0]) live = 1;   // benign race, any-write
    }
    __syncthreads();
    if (!live) break;                          // uniform: all comps merged
  }
}

// ---------------------------------------------------------------------------
// Enumeration sort: block b computes ranks of edges[4b..4b+3] among all
// (value,idx) pairs (unique -> permutation) and writes out[rank] = value.
// edges[] (16 KB) L2-broadcast to 1024 blocks. Dtype from cnt[2].
// ---------------------------------------------------------------------------
__global__ __launch_bounds__(256) void rank_sort(const float* edges,
                                                 const unsigned* cnt,
                                                 void* out) {
  __shared__ unsigned long long wred[4][2];
  const int b = blockIdx.x;          // pivots 4b..4b+3
  const int t = threadIdx.x;
  const int pbase = 4 * b;
  const float4* ev = (const float4*)edges;
  const float4 pvv = ev[b];          // the 4 pivot values (aligned)
  const float pv0 = pvv.x, pv1 = pvv.y, pv2 = pvv.z, pv3 = pvv.w;

  int c0 = 0, c1 = 0, c2 = 0, c3 = 0;
#pragma unroll
  for (int k = 0; k < 4; ++k) {
    float4 e = ev[t + 256 * k];
    int j = 4 * (t + 256 * k);
    float va[4] = {e.x, e.y, e.z, e.w};
#pragma unroll
    for (int m = 0; m < 4; ++m) {
      const float x = va[m];
      const int xi = j + m;
      c0 += (x < pv0 || (x == pv0 && xi < pbase + 0));
      c1 += (x < pv1 || (x == pv1 && xi < pbase + 1));
      c2 += (x < pv2 || (x == pv2 && xi < pbase + 2));
      c3 += (x < pv3 || (x == pv3 && xi < pbase + 3));
    }
  }

  // packed reductions: counts <= 4096 so 32-bit halves never interact
  unsigned long long p0 = (unsigned long long)(unsigned)c0 |
                          ((unsigned long long)(unsigned)c1 << 32);
  unsigned long long p1 = (unsigned long long)(unsigned)c2 |
                          ((unsigned long long)(unsigned)c3 << 32);
#pragma unroll
  for (int m = 1; m < 64; m <<= 1) {
    p0 += __shfl_xor(p0, m);
    p1 += __shfl_xor(p1, m);
  }
  if ((t & 63) == 0) { wred[t >> 6][0] = p0; wred[t >> 6][1] = p1; }
  __syncthreads();

  if (t == 0) {
    unsigned long long a = wred[0][0] + wred[1][0] + wred[2][0] + wred[3][0];
    unsigned long long d = wred[0][1] + wred[1][1] + wred[2][1] + wred[3][1];
    const int r[4] = {(int)(a & 0xFFFFFFFFull), (int)(a >> 32),
                      (int)(d & 0xFFFFFFFFull), (int)(d >> 32)};
    const float pv[4] = {pv0, pv1, pv2, pv3};
    const bool bf = cnt[2] != 0u;
#pragma unroll
    for (int p = 0; p < 4; ++p) {
      const int pidx = pbase + p;
      if (pidx < NPTS - 1) {     // pivot 4095 is the SENT sentinel
        if (bf) ((__hip_bfloat16*)out)[r[p]] = __float2bfloat16(pv[p]);
        else    ((float*)out)[r[p]] = pv[p];
      }
    }
  }
}

// ---------------------------------------------------------------------------
// Fallback kernels (verified R1/R4 path) for small-ws case.
// ---------------------------------------------------------------------------
__global__ __launch_bounds__(256) void dist_kernel(const void* pts_raw,
                                                   __hip_bfloat16* Dbf) {
  __shared__ float As[64 * 65];
  __shared__ float Bs[64 * 65];
  __shared__ float sqA[64];
  __shared__ float sqB[64];

  const int t = threadIdx.x;
  const int bx = blockIdx.x, by = blockIdx.y;
  const bool bf = data_is_bf16((const unsigned short*)pts_raw);
  const unsigned short* pu = (const unsigned short*)pts_raw;
  const float* pf = (const float*)pts_raw;

  for (int s = 0; s < 16; ++s) {
    int e = t + 256 * s;
    int r = e >> 6, c = e & 63;
    float av, bv;
    if (bf) {
      av = bfbits2f((unsigned int)pu[by * 4096 + e]);
      bv = bfbits2f((unsigned int)pu[bx * 4096 + e]);
    } else {
      av = pf[by * 4096 + e];
      bv = pf[bx * 4096 + e];
    }
    As[r * 65 + c] = av;
    Bs[r * 65 + c] = bv;
  }
  __syncthreads();

  if (t < 64) {
    float s = 0.f;
    for (int k = 0; k < 64; ++k) { float x = As[t * 65 + k]; s += x * x; }
    sqA[t] = s;
  } else if (t < 128) {
    int r = t - 64;
    float s = 0.f;
    for (int k = 0; k < 64; ++k) { float x = Bs[r * 65 + k]; s += x * x; }
    sqB[r] = s;
  }
  __syncthreads();

  const int tx = t & 15, ty = t >> 4;
  const int lr = ty * 4, lc = tx * 4;
  float acc[4][4] = {};
  for (int k = 0; k < 64; ++k) {
    float a[4], b[4];
#pragma unroll
    for (int q = 0; q < 4; ++q) a[q] = As[(lr + q) * 65 + k];
#pragma unroll
    for (int p = 0; p < 4; ++p) b[p] = Bs[(lc + p) * 65 + k];
#pragma unroll
    for (int q = 0; q < 4; ++q)
#pragma unroll
      for (int p = 0; p < 4; ++p) acc[q][p] += a[q] * b[p];
  }

#pragma unroll
  for (int q = 0; q < 4; ++q) {
    int gr = by * 64 + lr + q;
    float sa = sqA[lr + q];
#pragma unroll
    for (int p = 0; p < 4; ++p) {
      int gc = bx * 64 + lc + p;
      float d2 = sa + sqB[lc + p] - 2.f * acc[q][p];
      d2 = fmaxf(d2, 0.f);
      Dbf[(size_t)gr * 4096 + gc] = __float2bfloat16(sqrtf(d2));
    }
  }
}

__global__ __launch_bounds__(512) void prim_kernel(const unsigned short* probe,
                                                   const unsigned short* Dbf,
                                                   void* out) {
  __shared__ float len[NPTS];
  __shared__ float rv[2][8];
  __shared__ int ri[2][8];

  const int t = threadIdx.x;
  const bool bf_out = data_is_bf16(probe);

  float d[8];
  {
    const uint4* row0 = (const uint4*)(Dbf);
    uint4 v = row0[t];
    d[0] = bfbits2f(v.x & 0xffffu); d[1] = bfbits2f(v.x >> 16);
    d[2] = bfbits2f(v.y & 0xffffu); d[3] = bfbits2f(v.y >> 16);
    d[4] = bfbits2f(v.z & 0xffffu); d[5] = bfbits2f(v.z >> 16);
    d[6] = bfbits2f(v.w & 0xffffu); d[7] = bfbits2f(v.w >> 16);
    if (t == 0) d[0] = SENT;
  }

  float bv = SENT;
  int bi = 8 * t;
#pragma unroll
  for (int k = 0; k < 8; ++k)
    if (d[k] < bv) { bv = d[k]; bi = 8 * t + k; }

  for (int step = 0; step < NPTS - 1; ++step) {
    float v = bv;
    int idx = bi;
#pragma unroll
    for (int m = 1; m < 64; m <<= 1) {
      float ov = __shfl_xor(v, m);
      int oi = __shfl_xor(idx, m);
      if (ov < v) { v = ov; idx = oi; }
    }
    const int buf = step & 1;
    if ((t & 63) == 0) { rv[buf][t >> 6] = v; ri[buf][t >> 6] = idx; }
    __syncthreads();

    float w = rv[buf][0];
    int j = ri[buf][0];
#pragma unroll
    for (int u = 1; u < 8; ++u) {
      float uv = rv[buf][u];
      if (uv < w) { w = uv; j = ri[buf][u]; }
    }
    if (t == 0) len[step] = w;

    const uint4* row = (const uint4*)(Dbf + (size_t)j * NPTS);
    uint4 rw = row[t];
    float nd[8];
    nd[0] = bfbits2f(rw.x & 0xffffu); nd[1] = bfbits2f(rw.x >> 16);
    nd[2] = bfbits2f(rw.y & 0xffffu); nd[3] = bfbits2f(rw.y >> 16);
    nd[4] = bfbits2f(rw.z & 0xffffu); nd[5] = bfbits2f(rw.z >> 16);
    nd[6] = bfbits2f(rw.w & 0xffffu); nd[7] = bfbits2f(rw.w >> 16);

    bv = SENT;
    bi = 8 * t;
    const int base = 8 * t;
#pragma unroll
    for (int k = 0; k < 8; ++k) {
      float cur = d[k];
      float nn = fminf(cur, nd[k]);
      if (cur == SENT || base + k == j) nn = SENT;
      d[k] = nn;
      if (nn < bv) { bv = nn; bi = base + k; }
    }
  }

  if (t == 0) len[NPTS - 1] = SENT;
  __syncthreads();

  for (int k = 2; k <= NPTS; k <<= 1) {
    for (int jj = k >> 1; jj > 0; jj >>= 1) {
      for (int i = t; i < NPTS; i += 512) {
        int ixj = i ^ jj;
        if (ixj > i) {
          float a = len[i], b = len[ixj];
          bool up = ((i & k) == 0);
          if ((a > b) == up) { len[i] = b; len[ixj] = a; }
        }
      }
      __syncthreads();
    }
  }

  if (bf_out) {
    __hip_bfloat16* o = (__hip_bfloat16*)out;
    for (int i = t; i < NPTS - 1; i += 512) o[i] = __float2bfloat16(len[i]);
  } else {
    float* o = (float*)out;
    for (int i = t; i < NPTS - 1; i += 512) o[i] = len[i];
  }
}

extern "C" void kernel_launch(void* const* d_in, const int* in_sizes, int n_in,
                              void* d_out, int out_size, void* d_ws, size_t ws_size,
                              hipStream_t stream) {
  const void* pts = d_in[0];
  char* base = (char*)d_ws;
  __hip_bfloat16* Dbf = (__hip_bfloat16*)base;

  size_t off = 32ull << 20;                        // D: 32 MiB
  int* comp = (int*)(base + off);                  off += (size_t)NPTS * 4;
  int* parent = (int*)(base + off);                off += (size_t)NPTS * 4;
  unsigned long long* cheapest =
      (unsigned long long*)(base + off);           off += (size_t)NPTS * 8;
  float* edges = (float*)(base + off);             off += (size_t)NPTS * 4;
  unsigned* cnt = (unsigned*)(base + off);         off += 256;
  unsigned short* Pb = (unsigned short*)(base + off); off += (size_t)NPTS * 64 * 2;
  float* sq = (float*)(base + off);                off += (size_t)NPTS * 4;
  unsigned short* comp16 = (unsigned short*)(base + off); off += (size_t)NPTS * 2;
  unsigned* M = (unsigned*)(base + off);           off += (size_t)CMAX * CMAX * 4;
  unsigned long long* cheapM =
      (unsigned long long*)(base + off);           off += (size_t)CMAX * 8;

  if (ws_size >= off) {
    prep_kernel<<<1024, 256, 0, stream>>>(pts, Pb, sq, comp, comp16, parent,
                                          cheapest, edges, cnt, M, cheapM);
    const unsigned short* Dus = (const unsigned short*)Dbf;
    dist_mfma<<<dim3(64, 64), 256, 0, stream>>>(Pb, sq, (unsigned short*)Dbf,
                                                cheapest);
    // hook round 0 (cheapest filled by the fused scan in dist_mfma)
    bor_hook<<<1, 1024, 0, stream>>>(comp, comp16, parent, cheapest, edges,
                                     cnt, HOOK_NORMAL);
    // round 1: C <= 1024 guaranteed after this hook -> always compact
    bor_scan<<<SCAN_BLOCKS, 256, 0, stream>>>(Dus, comp16, parent, cheapest,
                                              cnt);
    bor_hook<<<1, 1024, 0, stream>>>(comp, comp16, parent, cheapest, edges,
                                     cnt, HOOK_FORCE_COMPACT);
    bor_project<<<SCAN_BLOCKS, 256, 0, stream>>>(Dus, comp16, M, cnt, cheapM);
    bor_finish<<<1, 1024, 0, stream>>>(M, cnt, edges, cheapM);
    rank_sort<<<NPTS / 4, 256, 0, stream>>>(edges, cnt, d_out);
  } else {
    dist_kernel<<<dim3(64, 64), 256, 0, stream>>>(pts, Dbf);
    prim_kernel<<<1, 512, 0, stream>>>((const unsigned short*)pts,
                                       (const unsigned short*)Dbf, d_out);
  }
}